// Round 1
// baseline (431.055 us; speedup 1.0000x reference)
//
#include <hip/hip_runtime.h>
#include <math.h>

// Problem constants
#define LQ   512
#define DS   384
#define DPAIR 128
#define NH   12
#define NP   1728   // 384*3 + 144*2 + 288
#define NPP  1792   // padded to multiple of 64
#define FE   48     // logits feature dim (32 q + 12 pts + 2)

// ---------------------------------------------------------------- concat W
__global__ void k_concat_w(const float* __restrict__ Wq, const float* __restrict__ Wk,
                           const float* __restrict__ Wv, const float* __restrict__ Wqp,
                           const float* __restrict__ Wkp, const float* __restrict__ Wvp,
                           const float* __restrict__ bq, const float* __restrict__ bk,
                           const float* __restrict__ bv, const float* __restrict__ bqp,
                           const float* __restrict__ bkp, const float* __restrict__ bvp,
                           float* __restrict__ Wcat, float* __restrict__ bcat) {
  int idx = blockIdx.x * 256 + threadIdx.x;
  const int total = DS * NPP;
  if (idx < total) {
    int k = idx / NPP, c = idx % NPP;
    float v = 0.f;
    if (c < 384)       v = Wq[k*384 + c];
    else if (c < 768)  v = Wk[k*384 + c-384];
    else if (c < 1152) v = Wv[k*384 + c-768];
    else if (c < 1296) v = Wqp[k*144 + c-1152];
    else if (c < 1440) v = Wkp[k*144 + c-1296];
    else if (c < 1728) v = Wvp[k*288 + c-1440];
    Wcat[idx] = v;
  } else if (idx < total + NPP) {
    int c = idx - total;
    float v = 0.f;
    if (c < 384)       v = bq[c];
    else if (c < 768)  v = bk[c-384];
    else if (c < 1152) v = bv[c-768];
    else if (c < 1296) v = bqp[c-1152];
    else if (c < 1440) v = bkp[c-1296];
    else if (c < 1728) v = bvp[c-1440];
    bcat[c] = v;
  }
}

// ---------------------------------------------------------------- layernorm
__global__ __launch_bounds__(128) void k_layernorm(const float* __restrict__ x,
                                                   const float* __restrict__ w,
                                                   const float* __restrict__ b,
                                                   float* __restrict__ y) {
  __shared__ float red[128];
  __shared__ float s_mu, s_rstd;
  int i = blockIdx.x, t = threadIdx.x;
  float v0 = x[i*DS + t], v1 = x[i*DS + t + 128], v2 = x[i*DS + t + 256];
  red[t] = v0 + v1 + v2; __syncthreads();
  for (int s = 64; s > 0; s >>= 1) { if (t < s) red[t] += red[t+s]; __syncthreads(); }
  if (t == 0) s_mu = red[0] * (1.f/384.f);
  __syncthreads();
  float mu = s_mu;
  float d0 = v0-mu, d1 = v1-mu, d2 = v2-mu;
  red[t] = d0*d0 + d1*d1 + d2*d2; __syncthreads();
  for (int s = 64; s > 0; s >>= 1) { if (t < s) red[t] += red[t+s]; __syncthreads(); }
  if (t == 0) s_rstd = rsqrtf(red[0] * (1.f/384.f) + 1e-5f);
  __syncthreads();
  float r = s_rstd;
  y[i*DS + t      ] = d0*r*w[t      ] + b[t      ];
  y[i*DS + t + 128] = d1*r*w[t + 128] + b[t + 128];
  y[i*DS + t + 256] = d2*r*w[t + 256] + b[t + 256];
}

// ---------------------------------------------------------------- tiled f32 GEMM (NN), 64x64 tile, 4x4 micro, optional split-K
__global__ __launch_bounds__(256) void k_gemm_nn(const float* __restrict__ A,
                                                 const float* __restrict__ B,
                                                 const float* __restrict__ bias,
                                                 float* __restrict__ C,
                                                 float* __restrict__ Cpart,
                                                 int M, int N, int K) {
  __shared__ float As[16*68];
  __shared__ float Bs[16*68];
  int t = threadIdx.x;
  int mg = t >> 4, ng = t & 15;
  int i0 = blockIdx.y * 64, j0 = blockIdx.x * 64;
  int KS = gridDim.z;
  int kper = K / KS;
  int kbeg = blockIdx.z * kper;
  float acc[4][4] = {};
  for (int k0 = kbeg; k0 < kbeg + kper; k0 += 16) {
    int e = t;
    #pragma unroll
    for (int s = 0; s < 4; s++, e += 256) {
      int m = e >> 4, k = e & 15;
      As[k*68 + m] = A[(size_t)(i0+m)*K + k0 + k];
      int k2 = e >> 6, n = e & 63;
      Bs[k2*68 + n] = B[(size_t)(k0+k2)*N + j0 + n];
    }
    __syncthreads();
    #pragma unroll
    for (int k = 0; k < 16; k++) {
      float4 av = *(const float4*)(As + k*68 + mg*4);
      float4 bv = *(const float4*)(Bs + k*68 + ng*4);
      float a[4] = {av.x, av.y, av.z, av.w};
      float b[4] = {bv.x, bv.y, bv.z, bv.w};
      #pragma unroll
      for (int y = 0; y < 4; y++)
        #pragma unroll
        for (int x = 0; x < 4; x++)
          acc[y][x] = fmaf(a[y], b[x], acc[y][x]);
    }
    __syncthreads();
  }
  if (KS == 1) {
    #pragma unroll
    for (int y = 0; y < 4; y++) {
      int m = i0 + mg*4 + y;
      #pragma unroll
      for (int x = 0; x < 4; x++) {
        int n = j0 + ng*4 + x;
        C[(size_t)m*N + n] = acc[y][x] + bias[n];
      }
    }
  } else {
    float* dst = Cpart + (size_t)blockIdx.z * M * N;
    #pragma unroll
    for (int y = 0; y < 4; y++) {
      int m = i0 + mg*4 + y;
      #pragma unroll
      for (int x = 0; x < 4; x++) {
        int n = j0 + ng*4 + x;
        dst[(size_t)m*N + n] = acc[y][x];
      }
    }
  }
}

__global__ void k_reduce_bias(const float* __restrict__ part, const float* __restrict__ bias,
                              float* __restrict__ out, int MN, int N, int KS) {
  int e = blockIdx.x * 256 + threadIdx.x;
  if (e >= MN) return;
  float s = bias[e % N];
  for (int z = 0; z < KS; z++) s += part[(size_t)z*MN + e];
  out[e] = s;
}

// ---------------------------------------------------------------- rotate points to global frame
__global__ void k_rotate(const float* __restrict__ C1, const float* __restrict__ rot,
                         const float* __restrict__ trans, float* __restrict__ qg,
                         float* __restrict__ kg, float* __restrict__ vg) {
  int idx = blockIdx.x * 256 + threadIdx.x;   // LQ*NH*16
  if (idx >= LQ*NH*16) return;
  int w = idx & 15; int h = (idx >> 4) % NH; int i = idx / (16*NH);
  const float* R = rot + (size_t)i*9;
  const float* tr = trans + (size_t)i*3;
  const float* src; float* dst;
  if (w < 4)      { src = C1 + (size_t)i*NPP + 1152 + h*12 + w*3;     dst = qg + ((size_t)i*NH + h)*12 + w*3; }
  else if (w < 8) { int p = w-4; src = C1 + (size_t)i*NPP + 1296 + h*12 + p*3; dst = kg + ((size_t)i*NH + h)*12 + p*3; }
  else            { int p = w-8; src = C1 + (size_t)i*NPP + 1440 + h*24 + p*3; dst = vg + ((size_t)i*NH + h)*24 + p*3; }
  float x = src[0], y = src[1], z = src[2];
  dst[0] = fmaf(R[0],x, fmaf(R[1],y, fmaf(R[2],z, tr[0])));
  dst[1] = fmaf(R[3],x, fmaf(R[4],y, fmaf(R[5],z, tr[1])));
  dst[2] = fmaf(R[6],x, fmaf(R[7],y, fmaf(R[8],z, tr[2])));
}

// ---------------------------------------------------------------- build 48-dim logits features
// A[h][i] = [s*q(32), gp*qg(12), -0.5*gp*|qg|^2, 1, 0,0]
// B[h][j] = [  k(32),     kg(12), 1, -0.5*gp*|kg|^2, 0,0]
__global__ void k_features(const float* __restrict__ C1, const float* __restrict__ qg,
                           const float* __restrict__ kg, const float* __restrict__ gamma,
                           const float* __restrict__ w_c, const float* __restrict__ w_l,
                           float* __restrict__ Af, float* __restrict__ Bf) {
  int idx = blockIdx.x * 256 + threadIdx.x;
  if (idx >= LQ*NH) return;
  int h = idx % NH, i = idx / NH;
  float s  = w_c[0] * rsqrtf(32.f);
  float gp = gamma[h] * w_l[0];
  float* a  = Af + ((size_t)h*LQ + i)*FE;
  float* bb = Bf + ((size_t)h*LQ + i)*FE;
  const float* q = C1 + (size_t)i*NPP + h*32;
  const float* k = C1 + (size_t)i*NPP + 384 + h*32;
  for (int d = 0; d < 32; d++) { a[d] = s*q[d]; bb[d] = k[d]; }
  const float* qp = qg + ((size_t)i*NH + h)*12;
  const float* kp = kg + ((size_t)i*NH + h)*12;
  float sq = 0.f, sk = 0.f;
  for (int d = 0; d < 12; d++) {
    float x = qp[d], y = kp[d];
    a[32+d] = gp*x; bb[32+d] = y;
    sq = fmaf(x,x,sq); sk = fmaf(y,y,sk);
  }
  a[44] = -0.5f*gp*sq; a[45] = 1.f; a[46] = 0.f; a[47] = 0.f;
  bb[44] = 1.f; bb[45] = -0.5f*gp*sk; bb[46] = 0.f; bb[47] = 0.f;
}

// ---------------------------------------------------------------- batched NT GEMM: S[h] = A_h @ B_h^T  (K=48)
__global__ __launch_bounds__(256) void k_logits_nt(const float* __restrict__ Af,
                                                   const float* __restrict__ Bf,
                                                   float* __restrict__ S) {
  __shared__ float As[48*68];
  __shared__ float Bs[48*68];
  int h = blockIdx.z;
  int i0 = blockIdx.y * 64, j0 = blockIdx.x * 64;
  int t = threadIdx.x;
  int mg = t >> 4, ng = t & 15;
  const float* Ah = Af + (size_t)h*LQ*FE;
  const float* Bh = Bf + (size_t)h*LQ*FE;
  for (int e = t; e < 64*48; e += 256) {
    int m = e / 48, k = e % 48;
    As[k*68 + m] = Ah[(size_t)(i0+m)*FE + k];
    Bs[k*68 + m] = Bh[(size_t)(j0+m)*FE + k];
  }
  __syncthreads();
  float acc[4][4] = {};
  #pragma unroll 8
  for (int k = 0; k < 48; k++) {
    float4 av = *(const float4*)(As + k*68 + mg*4);
    float4 bv = *(const float4*)(Bs + k*68 + ng*4);
    float a[4] = {av.x, av.y, av.z, av.w};
    float b[4] = {bv.x, bv.y, bv.z, bv.w};
    #pragma unroll
    for (int y = 0; y < 4; y++)
      #pragma unroll
      for (int x = 0; x < 4; x++)
        acc[y][x] = fmaf(a[y], b[x], acc[y][x]);
  }
  #pragma unroll
  for (int y = 0; y < 4; y++) {
    #pragma unroll
    for (int x = 0; x < 4; x++)
      S[((size_t)h*LQ + i0 + mg*4 + y)*LQ + j0 + ng*4 + x] = acc[y][x];
  }
}

// ---------------------------------------------------------------- pair bias: S[h,i,j] += pair[i,j,:]·Wpb[:,h] + bpb[h]
// one thread per (i,j); Wpb indices wave-uniform -> scalar loads
__global__ __launch_bounds__(256) void k_pair_bias(const float* __restrict__ pair,
                                                   const float* __restrict__ Wpb,
                                                   const float* __restrict__ bpb,
                                                   float* __restrict__ S) {
  int bid = blockIdx.x;           // 1024 blocks
  int i = bid >> 1;
  int j = (bid & 1) * 256 + threadIdx.x;
  const float* prow = pair + ((size_t)i*LQ + j) * DPAIR;
  float acc[NH];
  #pragma unroll
  for (int h = 0; h < NH; h++) acc[h] = bpb[h];
  for (int c4 = 0; c4 < 32; c4++) {
    float4 p = *(const float4*)(prow + c4*4);
    float pv[4] = {p.x, p.y, p.z, p.w};
    #pragma unroll
    for (int cc = 0; cc < 4; cc++) {
      #pragma unroll
      for (int h = 0; h < NH; h++)
        acc[h] = fmaf(pv[cc], Wpb[(c4*4+cc)*NH + h], acc[h]);
    }
  }
  #pragma unroll
  for (int h = 0; h < NH; h++) {
    size_t idx = ((size_t)h*LQ + i)*LQ + j;
    S[idx] += acc[h];
  }
}

// ---------------------------------------------------------------- softmax over j per (h,i); writes attn in place + attnT
__global__ __launch_bounds__(512) void k_softmax(float* __restrict__ S,
                                                 const float* __restrict__ mask,
                                                 float* __restrict__ attnT) {
  __shared__ float buf[NH*LQ];
  __shared__ float red[8];
  __shared__ float bcast;
  int i = blockIdx.x, t = threadIdx.x;
  int lane = t & 63, wv = t >> 6;
  float mi = mask[i];
  float mj = mask[t];
  for (int h = 0; h < NH; h++) {
    size_t idx = ((size_t)h*LQ + i)*LQ + t;
    float l = S[idx];
    if (mi*mj <= 0.f) l = -1e9f;
    float m = l;
    for (int o = 32; o > 0; o >>= 1) m = fmaxf(m, __shfl_xor(m, o, 64));
    if (lane == 0) red[wv] = m;
    __syncthreads();
    if (t == 0) { float mm = red[0]; for (int w2 = 1; w2 < 8; w2++) mm = fmaxf(mm, red[w2]); bcast = mm; }
    __syncthreads();
    float mx = bcast;
    float e = __expf(l - mx);
    float sm = e;
    for (int o = 32; o > 0; o >>= 1) sm += __shfl_xor(sm, o, 64);
    if (lane == 0) red[wv] = sm;
    __syncthreads();
    if (t == 0) { float ss = 0.f; for (int w2 = 0; w2 < 8; w2++) ss += red[w2]; bcast = ss; }
    __syncthreads();
    float a = e / bcast;
    buf[h*LQ + t] = a;
    S[idx] = a;
    __syncthreads();
  }
  // transposed copy attnT[i][j][h], coalesced 48B per lane
  #pragma unroll
  for (int h4 = 0; h4 < 3; h4++) {
    float4 v;
    v.x = buf[(h4*4+0)*LQ + t];
    v.y = buf[(h4*4+1)*LQ + t];
    v.z = buf[(h4*4+2)*LQ + t];
    v.w = buf[(h4*4+3)*LQ + t];
    *(float4*)(attnT + ((size_t)i*LQ + t)*NH + h4*4) = v;
  }
}

// ---------------------------------------------------------------- pair_out: comb[i, 768 + h*128 + d] = sum_j attn[h,i,j]*pair[i,j,d]
// lanes over d; attnT reads wave-uniform -> scalar loads
__global__ __launch_bounds__(128) void k_pair_out(const float* __restrict__ attnT,
                                                  const float* __restrict__ pair,
                                                  float* __restrict__ comb) {
  __shared__ float red[NH*128];
  int i = blockIdx.x, t = threadIdx.x;
  int d2 = t & 63;
  int js = t >> 6;   // 0,1: j parity
  int aoff = __builtin_amdgcn_readfirstlane(js * NH);
  const float* prow = pair + (size_t)i*LQ*DPAIR + 2*d2;
  const float* arow = attnT + (size_t)i*LQ*NH + aoff;
  float acc[NH][2] = {};
  for (int jj = 0; jj < 256; jj++) {
    int j = 2*jj + js;
    float2 p = *(const float2*)(prow + (size_t)j*DPAIR);
    const float* av = arow + jj*(2*NH);
    #pragma unroll
    for (int h = 0; h < NH; h++) {
      acc[h][0] = fmaf(av[h], p.x, acc[h][0]);
      acc[h][1] = fmaf(av[h], p.y, acc[h][1]);
    }
  }
  if (js == 1) {
    #pragma unroll
    for (int h = 0; h < NH; h++) {
      red[h*128 + 2*d2    ] = acc[h][0];
      red[h*128 + 2*d2 + 1] = acc[h][1];
    }
  }
  __syncthreads();
  if (js == 0) {
    #pragma unroll
    for (int h = 0; h < NH; h++) {
      float v0 = acc[h][0] + red[h*128 + 2*d2];
      float v1 = acc[h][1] + red[h*128 + 2*d2 + 1];
      float* dst = comb + (size_t)i*2304 + 768 + h*128 + 2*d2;
      dst[0] = v0; dst[1] = v1;
    }
  }
}

// ---------------------------------------------------------------- attn @ [v | vg] per head, split-K=4 -> psum
__global__ __launch_bounds__(256) void k_attn_v(const float* __restrict__ attn,
                                                const float* __restrict__ C1,
                                                const float* __restrict__ vg,
                                                float* __restrict__ psum) {
  __shared__ float As[64*68];   // [j][m] (transposed)
  __shared__ float Vs[64*68];   // [j][n], n<56 valid
  int i0 = blockIdx.x * 64;
  int h = blockIdx.y;
  int z = blockIdx.z;
  int t = threadIdx.x;
  int mg = t >> 4, ng = t & 15;
  float acc[4][4] = {};
  for (int k0 = z*128; k0 < z*128 + 128; k0 += 64) {
    __syncthreads();
    for (int e = t; e < 64*64; e += 256) {
      int m = e >> 6, j = e & 63;
      As[j*68 + m] = attn[((size_t)h*LQ + i0 + m)*LQ + k0 + j];
    }
    for (int e = t; e < 64*64; e += 256) {
      int j = e >> 6, c = e & 63;
      float v = 0.f;
      if (c < 32)      v = C1[(size_t)(k0+j)*NPP + 768 + h*32 + c];
      else if (c < 56) v = vg[((size_t)(k0+j)*NH + h)*24 + (c-32)];
      Vs[j*68 + c] = v;
    }
    __syncthreads();
    #pragma unroll 4
    for (int j = 0; j < 64; j++) {
      float4 av = *(const float4*)(As + j*68 + mg*4);
      float4 bv = *(const float4*)(Vs + j*68 + ng*4);
      float a[4] = {av.x, av.y, av.z, av.w};
      float b[4] = {bv.x, bv.y, bv.z, bv.w};
      #pragma unroll
      for (int y = 0; y < 4; y++)
        #pragma unroll
        for (int x = 0; x < 4; x++)
          acc[y][x] = fmaf(a[y], b[x], acc[y][x]);
    }
  }
  #pragma unroll
  for (int y = 0; y < 4; y++) {
    int i = i0 + mg*4 + y;
    #pragma unroll
    for (int x = 0; x < 4; x++) {
      int n = ng*4 + x;
      psum[(((size_t)z*LQ + i)*NH + h)*64 + n] = acc[y][x];
    }
  }
}

__global__ void k_av_reduce(const float* __restrict__ psum, float* __restrict__ comb,
                            float* __restrict__ pts) {
  int e = blockIdx.x * 256 + threadIdx.x;   // LQ*NH*56
  if (e >= LQ*NH*56) return;
  int n = e % 56; int ih = e / 56; int h = ih % NH; int i = ih / NH;
  size_t base = ((size_t)i*NH + h)*64 + n;
  float s = 0.f;
  for (int z = 0; z < 4; z++) s += psum[(size_t)z*LQ*NH*64 + base];
  if (n < 32) comb[(size_t)i*2304 + h*32 + n] = s;
  else        pts[((size_t)i*NH + h)*24 + (n-32)] = s;
}

// ---------------------------------------------------------------- point features: local frame + norm
__global__ void k_pts_feat(const float* __restrict__ pts, const float* __restrict__ rot,
                           const float* __restrict__ trans, float* __restrict__ comb) {
  int idx = blockIdx.x * 256 + threadIdx.x;   // LQ*NH*8
  if (idx >= LQ*NH*8) return;
  int p = idx & 7; int h = (idx >> 3) % NH; int i = idx / (8*NH);
  const float* R = rot + (size_t)i*9;
  const float* tr = trans + (size_t)i*3;
  const float* pt = pts + ((size_t)i*NH + h)*24 + p*3;
  float x = pt[0]-tr[0], y = pt[1]-tr[1], z = pt[2]-tr[2];
  float lx = fmaf(R[0],x, fmaf(R[3],y, R[6]*z));
  float ly = fmaf(R[1],x, fmaf(R[4],y, R[7]*z));
  float lz = fmaf(R[2],x, fmaf(R[5],y, R[8]*z));
  float nrm = sqrtf(fmaf(lx,lx, fmaf(ly,ly, lz*lz)));
  float* dst = comb + (size_t)i*2304 + 384 + (h*8 + p)*4;
  dst[0] = nrm; dst[1] = lx; dst[2] = ly; dst[3] = lz;
}

// ================================================================ launcher
extern "C" void kernel_launch(void* const* d_in, const int* in_sizes, int n_in,
                              void* d_out, int out_size, void* d_ws, size_t ws_size,
                              hipStream_t stream) {
  const float* single = (const float*)d_in[0];
  const float* pair   = (const float*)d_in[1];
  const float* rot    = (const float*)d_in[2];
  const float* trans  = (const float*)d_in[3];
  const float* mask   = (const float*)d_in[4];
  const float* ln_w   = (const float*)d_in[5];
  const float* ln_b   = (const float*)d_in[6];
  const float* Wq     = (const float*)d_in[7];
  const float* bq     = (const float*)d_in[8];
  const float* Wk     = (const float*)d_in[9];
  const float* bk     = (const float*)d_in[10];
  const float* Wv     = (const float*)d_in[11];
  const float* bv     = (const float*)d_in[12];
  const float* Wqp    = (const float*)d_in[13];
  const float* bqp    = (const float*)d_in[14];
  const float* Wkp    = (const float*)d_in[15];
  const float* bkp    = (const float*)d_in[16];
  const float* Wvp    = (const float*)d_in[17];
  const float* bvp    = (const float*)d_in[18];
  const float* Wpb    = (const float*)d_in[19];
  const float* bpb    = (const float*)d_in[20];
  const float* Wo     = (const float*)d_in[21];
  const float* bo     = (const float*)d_in[22];
  const float* w_c    = (const float*)d_in[23];
  const float* w_l    = (const float*)d_in[24];
  const float* gamma  = (const float*)d_in[25];
  float* out = (float*)d_out;

  float* p = (float*)d_ws;
  auto alloc = [&](size_t n) { float* r = p; p += n; return r; };
  float* Wcat   = alloc((size_t)DS*NPP);
  float* bcat   = alloc(NPP);
  float* sn     = alloc((size_t)LQ*DS);
  float* C1     = alloc((size_t)LQ*NPP);
  float* qg     = alloc((size_t)LQ*NH*12);
  float* kg     = alloc((size_t)LQ*NH*12);
  float* vgb    = alloc((size_t)LQ*NH*24);
  float* Af     = alloc((size_t)NH*LQ*FE);
  float* Bf     = alloc((size_t)NH*LQ*FE);
  float* S      = alloc((size_t)NH*LQ*LQ);
  float* attnT  = alloc((size_t)LQ*LQ*NH);
  float* comb   = alloc((size_t)LQ*2304);
  float* pts    = alloc((size_t)LQ*NH*24);
  float* scratch= alloc((size_t)8*LQ*DS);   // psum (4*512*12*64) and out-GEMM partials (8*512*384), both 1572864

  k_concat_w<<<dim3((DS*NPP + NPP + 255)/256), 256, 0, stream>>>(
      Wq, Wk, Wv, Wqp, Wkp, Wvp, bq, bk, bv, bqp, bkp, bvp, Wcat, bcat);
  k_layernorm<<<dim3(LQ), 128, 0, stream>>>(single, ln_w, ln_b, sn);
  k_gemm_nn<<<dim3(NPP/64, LQ/64, 1), 256, 0, stream>>>(sn, Wcat, bcat, C1, nullptr, LQ, NPP, DS);
  k_rotate<<<dim3((LQ*NH*16 + 255)/256), 256, 0, stream>>>(C1, rot, trans, qg, kg, vgb);
  k_features<<<dim3((LQ*NH + 255)/256), 256, 0, stream>>>(C1, qg, kg, gamma, w_c, w_l, Af, Bf);
  k_logits_nt<<<dim3(LQ/64, LQ/64, NH), 256, 0, stream>>>(Af, Bf, S);
  k_pair_bias<<<dim3(LQ*2), 256, 0, stream>>>(pair, Wpb, bpb, S);
  k_softmax<<<dim3(LQ), 512, 0, stream>>>(S, mask, attnT);
  k_pair_out<<<dim3(LQ), 128, 0, stream>>>(attnT, pair, comb);
  k_attn_v<<<dim3(LQ/64, NH, 4), 256, 0, stream>>>(S, C1, vgb, scratch);
  k_av_reduce<<<dim3((LQ*NH*56 + 255)/256), 256, 0, stream>>>(scratch, comb, pts);
  k_pts_feat<<<dim3((LQ*NH*8 + 255)/256), 256, 0, stream>>>(pts, rot, trans, comb);
  k_gemm_nn<<<dim3(DS/64, LQ/64, 8), 256, 0, stream>>>(comb, Wo, bo, nullptr, scratch, LQ, DS, 2304);
  k_reduce_bias<<<dim3((LQ*DS + 255)/256), 256, 0, stream>>>(scratch, bo, out, LQ*DS, DS, 8);
}

// Round 2
// 418.022 us; speedup vs baseline: 1.0312x; 1.0312x over previous
//
#include <hip/hip_runtime.h>
#include <math.h>

// Problem constants
#define LQ   512
#define DS   384
#define DPAIR 128
#define NH   12
#define NPP  1792   // padded projection width
#define FE   48     // logits feature dim (32 q + 12 pts + 2)
#define TJ   128    // j-tile for fused pair kernel

// ---------------------------------------------------------------- concat W
__global__ void k_concat_w(const float* __restrict__ Wq, const float* __restrict__ Wk,
                           const float* __restrict__ Wv, const float* __restrict__ Wqp,
                           const float* __restrict__ Wkp, const float* __restrict__ Wvp,
                           const float* __restrict__ bq, const float* __restrict__ bk,
                           const float* __restrict__ bv, const float* __restrict__ bqp,
                           const float* __restrict__ bkp, const float* __restrict__ bvp,
                           float* __restrict__ Wcat, float* __restrict__ bcat) {
  int idx = blockIdx.x * 256 + threadIdx.x;
  const int total = DS * NPP;
  if (idx < total) {
    int k = idx / NPP, c = idx % NPP;
    float v = 0.f;
    if (c < 384)       v = Wq[k*384 + c];
    else if (c < 768)  v = Wk[k*384 + c-384];
    else if (c < 1152) v = Wv[k*384 + c-768];
    else if (c < 1296) v = Wqp[k*144 + c-1152];
    else if (c < 1440) v = Wkp[k*144 + c-1296];
    else if (c < 1728) v = Wvp[k*288 + c-1440];
    Wcat[idx] = v;
  } else if (idx < total + NPP) {
    int c = idx - total;
    float v = 0.f;
    if (c < 384)       v = bq[c];
    else if (c < 768)  v = bk[c-384];
    else if (c < 1152) v = bv[c-768];
    else if (c < 1296) v = bqp[c-1152];
    else if (c < 1440) v = bkp[c-1296];
    else if (c < 1728) v = bvp[c-1440];
    bcat[c] = v;
  }
}

// transpose Wpb[k][h] -> WpbT[h][k] so the fused kernel can read it as float4
__global__ void k_wpbt(const float* __restrict__ Wpb, float* __restrict__ WpbT) {
  int e = blockIdx.x * 256 + threadIdx.x;
  if (e >= DPAIR * NH) return;
  int k = e / NH, h = e % NH;
  WpbT[h*DPAIR + k] = Wpb[e];
}

// ---------------------------------------------------------------- layernorm
__global__ __launch_bounds__(128) void k_layernorm(const float* __restrict__ x,
                                                   const float* __restrict__ w,
                                                   const float* __restrict__ b,
                                                   float* __restrict__ y) {
  __shared__ float red[128];
  __shared__ float s_mu, s_rstd;
  int i = blockIdx.x, t = threadIdx.x;
  float v0 = x[i*DS + t], v1 = x[i*DS + t + 128], v2 = x[i*DS + t + 256];
  red[t] = v0 + v1 + v2; __syncthreads();
  for (int s = 64; s > 0; s >>= 1) { if (t < s) red[t] += red[t+s]; __syncthreads(); }
  if (t == 0) s_mu = red[0] * (1.f/384.f);
  __syncthreads();
  float mu = s_mu;
  float d0 = v0-mu, d1 = v1-mu, d2 = v2-mu;
  red[t] = d0*d0 + d1*d1 + d2*d2; __syncthreads();
  for (int s = 64; s > 0; s >>= 1) { if (t < s) red[t] += red[t+s]; __syncthreads(); }
  if (t == 0) s_rstd = rsqrtf(red[0] * (1.f/384.f) + 1e-5f);
  __syncthreads();
  float r = s_rstd;
  y[i*DS + t      ] = d0*r*w[t      ] + b[t      ];
  y[i*DS + t + 128] = d1*r*w[t + 128] + b[t + 128];
  y[i*DS + t + 256] = d2*r*w[t + 256] + b[t + 256];
}

// ---------------------------------------------------------------- tiled f32 GEMM (NN), 64x64 tile, 4x4 micro, optional split-K
__global__ __launch_bounds__(256) void k_gemm_nn(const float* __restrict__ A,
                                                 const float* __restrict__ B,
                                                 const float* __restrict__ bias,
                                                 float* __restrict__ C,
                                                 float* __restrict__ Cpart,
                                                 int M, int N, int K) {
  __shared__ float As[16*68];
  __shared__ float Bs[16*68];
  int t = threadIdx.x;
  int mg = t >> 4, ng = t & 15;
  int i0 = blockIdx.y * 64, j0 = blockIdx.x * 64;
  int KS = gridDim.z;
  int kper = K / KS;
  int kbeg = blockIdx.z * kper;
  float acc[4][4] = {};
  for (int k0 = kbeg; k0 < kbeg + kper; k0 += 16) {
    int e = t;
    #pragma unroll
    for (int s = 0; s < 4; s++, e += 256) {
      int m = e >> 4, k = e & 15;
      As[k*68 + m] = A[(size_t)(i0+m)*K + k0 + k];
      int k2 = e >> 6, n = e & 63;
      Bs[k2*68 + n] = B[(size_t)(k0+k2)*N + j0 + n];
    }
    __syncthreads();
    #pragma unroll
    for (int k = 0; k < 16; k++) {
      float4 av = *(const float4*)(As + k*68 + mg*4);
      float4 bv = *(const float4*)(Bs + k*68 + ng*4);
      float a[4] = {av.x, av.y, av.z, av.w};
      float b[4] = {bv.x, bv.y, bv.z, bv.w};
      #pragma unroll
      for (int y = 0; y < 4; y++)
        #pragma unroll
        for (int x = 0; x < 4; x++)
          acc[y][x] = fmaf(a[y], b[x], acc[y][x]);
    }
    __syncthreads();
  }
  if (KS == 1) {
    #pragma unroll
    for (int y = 0; y < 4; y++) {
      int m = i0 + mg*4 + y;
      #pragma unroll
      for (int x = 0; x < 4; x++) {
        int n = j0 + ng*4 + x;
        C[(size_t)m*N + n] = acc[y][x] + bias[n];
      }
    }
  } else {
    float* dst = Cpart + (size_t)blockIdx.z * M * N;
    #pragma unroll
    for (int y = 0; y < 4; y++) {
      int m = i0 + mg*4 + y;
      #pragma unroll
      for (int x = 0; x < 4; x++) {
        int n = j0 + ng*4 + x;
        dst[(size_t)m*N + n] = acc[y][x];
      }
    }
  }
}

__global__ void k_reduce_bias(const float* __restrict__ part, const float* __restrict__ bias,
                              float* __restrict__ out, int MN, int N, int KS) {
  int e = blockIdx.x * 256 + threadIdx.x;
  if (e >= MN) return;
  float s = bias[e % N];
  for (int z = 0; z < KS; z++) s += part[(size_t)z*MN + e];
  out[e] = s;
}

// ---------------------------------------------------------------- rotate points to global frame
__global__ void k_rotate(const float* __restrict__ C1, const float* __restrict__ rot,
                         const float* __restrict__ trans, float* __restrict__ qg,
                         float* __restrict__ kg, float* __restrict__ vg) {
  int idx = blockIdx.x * 256 + threadIdx.x;   // LQ*NH*16
  if (idx >= LQ*NH*16) return;
  int w = idx & 15; int h = (idx >> 4) % NH; int i = idx / (16*NH);
  const float* R = rot + (size_t)i*9;
  const float* tr = trans + (size_t)i*3;
  const float* src; float* dst;
  if (w < 4)      { src = C1 + (size_t)i*NPP + 1152 + h*12 + w*3;     dst = qg + ((size_t)i*NH + h)*12 + w*3; }
  else if (w < 8) { int p = w-4; src = C1 + (size_t)i*NPP + 1296 + h*12 + p*3; dst = kg + ((size_t)i*NH + h)*12 + p*3; }
  else            { int p = w-8; src = C1 + (size_t)i*NPP + 1440 + h*24 + p*3; dst = vg + ((size_t)i*NH + h)*24 + p*3; }
  float x = src[0], y = src[1], z = src[2];
  dst[0] = fmaf(R[0],x, fmaf(R[1],y, fmaf(R[2],z, tr[0])));
  dst[1] = fmaf(R[3],x, fmaf(R[4],y, fmaf(R[5],z, tr[1])));
  dst[2] = fmaf(R[6],x, fmaf(R[7],y, fmaf(R[8],z, tr[2])));
}

// ---------------------------------------------------------------- build 48-dim logits features
__global__ void k_features(const float* __restrict__ C1, const float* __restrict__ qg,
                           const float* __restrict__ kg, const float* __restrict__ gamma,
                           const float* __restrict__ w_c, const float* __restrict__ w_l,
                           float* __restrict__ Af, float* __restrict__ Bf) {
  int idx = blockIdx.x * 256 + threadIdx.x;
  if (idx >= LQ*NH) return;
  int h = idx % NH, i = idx / NH;
  float s  = w_c[0] * rsqrtf(32.f);
  float gp = gamma[h] * w_l[0];
  float* a  = Af + ((size_t)h*LQ + i)*FE;
  float* bb = Bf + ((size_t)h*LQ + i)*FE;
  const float* q = C1 + (size_t)i*NPP + h*32;
  const float* k = C1 + (size_t)i*NPP + 384 + h*32;
  for (int d = 0; d < 32; d++) { a[d] = s*q[d]; bb[d] = k[d]; }
  const float* qp = qg + ((size_t)i*NH + h)*12;
  const float* kp = kg + ((size_t)i*NH + h)*12;
  float sq = 0.f, sk = 0.f;
  for (int d = 0; d < 12; d++) {
    float x = qp[d], y = kp[d];
    a[32+d] = gp*x; bb[32+d] = y;
    sq = fmaf(x,x,sq); sk = fmaf(y,y,sk);
  }
  a[44] = -0.5f*gp*sq; a[45] = 1.f; a[46] = 0.f; a[47] = 0.f;
  bb[44] = 1.f; bb[45] = -0.5f*gp*sk; bb[46] = 0.f; bb[47] = 0.f;
}

// ---------------------------------------------------------------- batched NT GEMM: S[h] = A_h @ B_h^T  (K=48)
__global__ __launch_bounds__(256) void k_logits_nt(const float* __restrict__ Af,
                                                   const float* __restrict__ Bf,
                                                   float* __restrict__ S) {
  __shared__ float As[48*68];
  __shared__ float Bs[48*68];
  int h = blockIdx.z;
  int i0 = blockIdx.y * 64, j0 = blockIdx.x * 64;
  int t = threadIdx.x;
  int mg = t >> 4, ng = t & 15;
  const float* Ah = Af + (size_t)h*LQ*FE;
  const float* Bh = Bf + (size_t)h*LQ*FE;
  for (int e = t; e < 64*48; e += 256) {
    int m = e / 48, k = e % 48;
    As[k*68 + m] = Ah[(size_t)(i0+m)*FE + k];
    Bs[k*68 + m] = Bh[(size_t)(j0+m)*FE + k];
  }
  __syncthreads();
  float acc[4][4] = {};
  #pragma unroll 8
  for (int k = 0; k < 48; k++) {
    float4 av = *(const float4*)(As + k*68 + mg*4);
    float4 bv = *(const float4*)(Bs + k*68 + ng*4);
    float a[4] = {av.x, av.y, av.z, av.w};
    float b[4] = {bv.x, bv.y, bv.z, bv.w};
    #pragma unroll
    for (int y = 0; y < 4; y++)
      #pragma unroll
      for (int x = 0; x < 4; x++)
        acc[y][x] = fmaf(a[y], b[x], acc[y][x]);
  }
  #pragma unroll
  for (int y = 0; y < 4; y++) {
    #pragma unroll
    for (int x = 0; x < 4; x++)
      S[((size_t)h*LQ + i0 + mg*4 + y)*LQ + j0 + ng*4 + x] = acc[y][x];
  }
}

// ---------------------------------------------------------------- FUSED: pair bias + online softmax + pair_out
// One block per i. Single streaming pass over pair[i,:,:] (134 MB total).
// In: S holds seq+geo logits. Out: S holds normalized attn; comb gets pair_out.
__global__ __launch_bounds__(512, 2) void k_pair_fused(
    const float* __restrict__ pair, const float* __restrict__ WpbT,
    const float* __restrict__ bpb, const float* __restrict__ mask,
    float* __restrict__ S, float* __restrict__ comb) {
  __shared__ float tile[TJ*133];        // 68.1 KB, padded stride 133 (conflict-free)
  __shared__ float logit[NH*LQ];        // 24 KB
  __shared__ float wt[NH*TJ];           // 6 KB  e^{l-m} for current tile
  __shared__ float m_s[NH], s_s[NH], alpha_s[NH];
  int i = blockIdx.x, t = threadIdx.x;
  float mi = mask[i];

  // preload logits (+ bpb), init online-softmax state
  for (int e = t; e < NH*LQ; e += 512) {
    int h = e >> 9, j = e & 511;
    logit[e] = S[((size_t)h*LQ + i)*LQ + j] + bpb[h];
  }
  if (t < NH) { m_s[t] = -3.0e38f; s_s[t] = 0.f; alpha_s[t] = 0.f; }

  const float* psrc = pair + (size_t)i*LQ*DPAIR;
  float4 r[8];
  // preload tile 0 into registers
  #pragma unroll
  for (int u = 0; u < 8; u++) r[u] = ((const float4*)psrc)[t + u*512];

  float4 acc[NH];
  #pragma unroll
  for (int h = 0; h < NH; h++) acc[h] = make_float4(0.f,0.f,0.f,0.f);

  for (int jt = 0; jt < LQ/TJ; jt++) {
    // stage registers -> LDS tile
    #pragma unroll
    for (int u = 0; u < 8; u++) {
      int e = t + u*512; int row = e >> 5, c4 = e & 31;
      *(float4*)&tile[row*133 + c4*4] = r[u];
    }
    __syncthreads();
    // issue next tile's loads (overlap with compute below)
    if (jt < LQ/TJ - 1) {
      const float4* nsrc = (const float4*)(psrc + (size_t)(jt+1)*TJ*DPAIR);
      #pragma unroll
      for (int u = 0; u < 8; u++) r[u] = nsrc[t + u*512];
    }

    // ---- phase A: pair-bias GEMV for this tile's j range
    {
      int j = t & 127;
      int hg = __builtin_amdgcn_readfirstlane(t >> 7);   // wave-uniform
      const float* w0p = WpbT + (hg*3+0)*DPAIR;
      const float* w1p = WpbT + (hg*3+1)*DPAIR;
      const float* w2p = WpbT + (hg*3+2)*DPAIR;
      float a0 = 0.f, a1 = 0.f, a2 = 0.f;
      #pragma unroll 8
      for (int k = 0; k < DPAIR; k += 4) {
        float4 pv = *(const float4*)&tile[j*133 + k];
        float4 w0 = *(const float4*)(w0p + k);
        float4 w1 = *(const float4*)(w1p + k);
        float4 w2 = *(const float4*)(w2p + k);
        a0 = fmaf(pv.x,w0.x, fmaf(pv.y,w0.y, fmaf(pv.z,w0.z, fmaf(pv.w,w0.w, a0))));
        a1 = fmaf(pv.x,w1.x, fmaf(pv.y,w1.y, fmaf(pv.z,w1.z, fmaf(pv.w,w1.w, a1))));
        a2 = fmaf(pv.x,w2.x, fmaf(pv.y,w2.y, fmaf(pv.z,w2.z, fmaf(pv.w,w2.w, a2))));
      }
      int jj = jt*TJ + j;
      bool dead = (mi * mask[jj] <= 0.f);
      int h0 = hg*3;
      float l0 = logit[(h0+0)*LQ + jj] + a0;
      float l1 = logit[(h0+1)*LQ + jj] + a1;
      float l2 = logit[(h0+2)*LQ + jj] + a2;
      if (dead) { l0 = -1e9f; l1 = -1e9f; l2 = -1e9f; }
      logit[(h0+0)*LQ + jj] = l0;
      logit[(h0+1)*LQ + jj] = l1;
      logit[(h0+2)*LQ + jj] = l2;
    }
    __syncthreads();

    // ---- online softmax: tile max, alpha, weights, running sum
    float lv[4];
    int sh = t >> 5, sl = t & 31;
    if (t < NH*32) {
      float mx = -3.0e38f;
      #pragma unroll
      for (int q = 0; q < 4; q++) {
        lv[q] = logit[sh*LQ + jt*TJ + sl + q*32];
        mx = fmaxf(mx, lv[q]);
      }
      #pragma unroll
      for (int o = 16; o > 0; o >>= 1) mx = fmaxf(mx, __shfl_xor(mx, o));
      if (sl == 0) {
        float mo = m_s[sh];
        float mn = fmaxf(mo, mx);
        alpha_s[sh] = __expf(mo - mn);
        m_s[sh] = mn;
      }
    }
    __syncthreads();
    if (t < NH*32) {
      float mn = m_s[sh];
      float sm = 0.f;
      #pragma unroll
      for (int q = 0; q < 4; q++) {
        float w = __expf(lv[q] - mn);
        wt[sh*TJ + sl + q*32] = w;
        sm += w;
      }
      #pragma unroll
      for (int o = 16; o > 0; o >>= 1) sm += __shfl_xor(sm, o);
      if (sl == 0) s_s[sh] = s_s[sh]*alpha_s[sh] + sm;
    }
    __syncthreads();

    // ---- phase C: accumulate pair_out from the same tile
    {
      int dg = t & 31, strip = t >> 5;   // 16 strips x 8 j
      int jb = strip*8;
      float4 pv[8];
      #pragma unroll
      for (int q = 0; q < 8; q++) pv[q] = *(const float4*)&tile[(jb+q)*133 + dg*4];
      #pragma unroll
      for (int h = 0; h < NH; h++) {
        float al = alpha_s[h];
        float4 w0 = *(const float4*)&wt[h*TJ + jb];
        float4 w1 = *(const float4*)&wt[h*TJ + jb + 4];
        float wq[8] = {w0.x,w0.y,w0.z,w0.w,w1.x,w1.y,w1.z,w1.w};
        float4 a = acc[h];
        a.x *= al; a.y *= al; a.z *= al; a.w *= al;
        #pragma unroll
        for (int q = 0; q < 8; q++) {
          a.x = fmaf(wq[q], pv[q].x, a.x);
          a.y = fmaf(wq[q], pv[q].y, a.y);
          a.z = fmaf(wq[q], pv[q].z, a.z);
          a.w = fmaf(wq[q], pv[q].w, a.w);
        }
        acc[h] = a;
      }
    }
    __syncthreads();   // tile consumed; safe to overwrite next iteration
  }

  // ---- epilogue 1: write normalized attention to S
  for (int e = t; e < NH*LQ; e += 512) {
    int h = e >> 9, j = e & 511;
    float a = __expf(logit[e] - m_s[h]) / s_s[h];
    S[((size_t)h*LQ + i)*LQ + j] = a;
  }

  // ---- epilogue 2: reduce pair_out across the 16 strips (reuse tile as scratch)
  float4* red4 = (float4*)tile;   // capacity 4256 float4 >= 8*12*32
  int dg = t & 31, strip = t >> 5;
  float4 tot = make_float4(0.f,0.f,0.f,0.f);
  #pragma unroll
  for (int half = 0; half < 2; half++) {
    if ((strip >> 3) == half) {
      #pragma unroll
      for (int h = 0; h < NH; h++) red4[((strip & 7)*NH + h)*32 + dg] = acc[h];
    }
    __syncthreads();
    if (t < NH*32) {
      int h = t >> 5, d = t & 31;
      #pragma unroll
      for (int s8 = 0; s8 < 8; s8++) {
        float4 v = red4[(s8*NH + h)*32 + d];
        tot.x += v.x; tot.y += v.y; tot.z += v.z; tot.w += v.w;
      }
    }
    __syncthreads();
  }
  if (t < NH*32) {
    int h = t >> 5, d = t & 31;
    float is = 1.f / s_s[h];
    float4 o = make_float4(tot.x*is, tot.y*is, tot.z*is, tot.w*is);
    *(float4*)&comb[(size_t)i*2304 + 768 + h*DPAIR + d*4] = o;
  }
}

// ---------------------------------------------------------------- attn @ [v | vg] per head, split-K=4 -> psum
__global__ __launch_bounds__(256) void k_attn_v(const float* __restrict__ attn,
                                                const float* __restrict__ C1,
                                                const float* __restrict__ vg,
                                                float* __restrict__ psum) {
  __shared__ float As[64*68];   // [j][m] (transposed)
  __shared__ float Vs[64*68];   // [j][n], n<56 valid
  int i0 = blockIdx.x * 64;
  int h = blockIdx.y;
  int z = blockIdx.z;
  int t = threadIdx.x;
  int mg = t >> 4, ng = t & 15;
  float acc[4][4] = {};
  for (int k0 = z*128; k0 < z*128 + 128; k0 += 64) {
    __syncthreads();
    for (int e = t; e < 64*64; e += 256) {
      int m = e >> 6, j = e & 63;
      As[j*68 + m] = attn[((size_t)h*LQ + i0 + m)*LQ + k0 + j];
    }
    for (int e = t; e < 64*64; e += 256) {
      int j = e >> 6, c = e & 63;
      float v = 0.f;
      if (c < 32)      v = C1[(size_t)(k0+j)*NPP + 768 + h*32 + c];
      else if (c < 56) v = vg[((size_t)(k0+j)*NH + h)*24 + (c-32)];
      Vs[j*68 + c] = v;
    }
    __syncthreads();
    #pragma unroll 4
    for (int j = 0; j < 64; j++) {
      float4 av = *(const float4*)(As + j*68 + mg*4);
      float4 bv = *(const float4*)(Vs + j*68 + ng*4);
      float a[4] = {av.x, av.y, av.z, av.w};
      float b[4] = {bv.x, bv.y, bv.z, bv.w};
      #pragma unroll
      for (int y = 0; y < 4; y++)
        #pragma unroll
        for (int x = 0; x < 4; x++)
          acc[y][x] = fmaf(a[y], b[x], acc[y][x]);
    }
  }
  #pragma unroll
  for (int y = 0; y < 4; y++) {
    int i = i0 + mg*4 + y;
    #pragma unroll
    for (int x = 0; x < 4; x++) {
      int n = ng*4 + x;
      psum[(((size_t)z*LQ + i)*NH + h)*64 + n] = acc[y][x];
    }
  }
}

__global__ void k_av_reduce(const float* __restrict__ psum, float* __restrict__ comb,
                            float* __restrict__ pts) {
  int e = blockIdx.x * 256 + threadIdx.x;   // LQ*NH*56
  if (e >= LQ*NH*56) return;
  int n = e % 56; int ih = e / 56; int h = ih % NH; int i = ih / NH;
  size_t base = ((size_t)i*NH + h)*64 + n;
  float s = 0.f;
  for (int z = 0; z < 4; z++) s += psum[(size_t)z*LQ*NH*64 + base];
  if (n < 32) comb[(size_t)i*2304 + h*32 + n] = s;
  else        pts[((size_t)i*NH + h)*24 + (n-32)] = s;
}

// ---------------------------------------------------------------- point features: local frame + norm
__global__ void k_pts_feat(const float* __restrict__ pts, const float* __restrict__ rot,
                           const float* __restrict__ trans, float* __restrict__ comb) {
  int idx = blockIdx.x * 256 + threadIdx.x;   // LQ*NH*8
  if (idx >= LQ*NH*8) return;
  int p = idx & 7; int h = (idx >> 3) % NH; int i = idx / (8*NH);
  const float* R = rot + (size_t)i*9;
  const float* tr = trans + (size_t)i*3;
  const float* pt = pts + ((size_t)i*NH + h)*24 + p*3;
  float x = pt[0]-tr[0], y = pt[1]-tr[1], z = pt[2]-tr[2];
  float lx = fmaf(R[0],x, fmaf(R[3],y, R[6]*z));
  float ly = fmaf(R[1],x, fmaf(R[4],y, R[7]*z));
  float lz = fmaf(R[2],x, fmaf(R[5],y, R[8]*z));
  float nrm = sqrtf(fmaf(lx,lx, fmaf(ly,ly, lz*lz)));
  float* dst = comb + (size_t)i*2304 + 384 + (h*8 + p)*4;
  dst[0] = nrm; dst[1] = lx; dst[2] = ly; dst[3] = lz;
}

// ================================================================ launcher
extern "C" void kernel_launch(void* const* d_in, const int* in_sizes, int n_in,
                              void* d_out, int out_size, void* d_ws, size_t ws_size,
                              hipStream_t stream) {
  const float* single = (const float*)d_in[0];
  const float* pair   = (const float*)d_in[1];
  const float* rot    = (const float*)d_in[2];
  const float* trans  = (const float*)d_in[3];
  const float* mask   = (const float*)d_in[4];
  const float* ln_w   = (const float*)d_in[5];
  const float* ln_b   = (const float*)d_in[6];
  const float* Wq     = (const float*)d_in[7];
  const float* bq     = (const float*)d_in[8];
  const float* Wk     = (const float*)d_in[9];
  const float* bk     = (const float*)d_in[10];
  const float* Wv     = (const float*)d_in[11];
  const float* bv     = (const float*)d_in[12];
  const float* Wqp    = (const float*)d_in[13];
  const float* bqp    = (const float*)d_in[14];
  const float* Wkp    = (const float*)d_in[15];
  const float* bkp    = (const float*)d_in[16];
  const float* Wvp    = (const float*)d_in[17];
  const float* bvp    = (const float*)d_in[18];
  const float* Wpb    = (const float*)d_in[19];
  const float* bpb    = (const float*)d_in[20];
  const float* Wo     = (const float*)d_in[21];
  const float* bo     = (const float*)d_in[22];
  const float* w_c    = (const float*)d_in[23];
  const float* w_l    = (const float*)d_in[24];
  const float* gamma  = (const float*)d_in[25];
  float* out = (float*)d_out;

  float* p = (float*)d_ws;
  auto alloc = [&](size_t n) { float* r = p; p += n; return r; };
  float* Wcat   = alloc((size_t)DS*NPP);
  float* bcat   = alloc(NPP);
  float* WpbT   = alloc((size_t)NH*DPAIR);
  float* sn     = alloc((size_t)LQ*DS);
  float* C1     = alloc((size_t)LQ*NPP);
  float* qg     = alloc((size_t)LQ*NH*12);
  float* kg     = alloc((size_t)LQ*NH*12);
  float* vgb    = alloc((size_t)LQ*NH*24);
  float* Af     = alloc((size_t)NH*LQ*FE);
  float* Bf     = alloc((size_t)NH*LQ*FE);
  float* S      = alloc((size_t)NH*LQ*LQ);
  float* comb   = alloc((size_t)LQ*2304);
  float* pts    = alloc((size_t)LQ*NH*24);
  float* scratch= alloc((size_t)8*LQ*DS);   // psum / out-GEMM partials

  k_concat_w<<<dim3((DS*NPP + NPP + 255)/256), 256, 0, stream>>>(
      Wq, Wk, Wv, Wqp, Wkp, Wvp, bq, bk, bv, bqp, bkp, bvp, Wcat, bcat);
  k_wpbt<<<dim3((DPAIR*NH + 255)/256), 256, 0, stream>>>(Wpb, WpbT);
  k_layernorm<<<dim3(LQ), 128, 0, stream>>>(single, ln_w, ln_b, sn);
  k_gemm_nn<<<dim3(NPP/64, LQ/64, 1), 256, 0, stream>>>(sn, Wcat, bcat, C1, nullptr, LQ, NPP, DS);
  k_rotate<<<dim3((LQ*NH*16 + 255)/256), 256, 0, stream>>>(C1, rot, trans, qg, kg, vgb);
  k_features<<<dim3((LQ*NH + 255)/256), 256, 0, stream>>>(C1, qg, kg, gamma, w_c, w_l, Af, Bf);
  k_logits_nt<<<dim3(LQ/64, LQ/64, NH), 256, 0, stream>>>(Af, Bf, S);
  k_pair_fused<<<dim3(LQ), 512, 0, stream>>>(pair, WpbT, bpb, mask, S, comb);
  k_attn_v<<<dim3(LQ/64, NH, 4), 256, 0, stream>>>(S, C1, vgb, scratch);
  k_av_reduce<<<dim3((LQ*NH*56 + 255)/256), 256, 0, stream>>>(scratch, comb, pts);
  k_pts_feat<<<dim3((LQ*NH*8 + 255)/256), 256, 0, stream>>>(pts, rot, trans, comb);
  k_gemm_nn<<<dim3(DS/64, LQ/64, 8), 256, 0, stream>>>(comb, Wo, bo, nullptr, scratch, LQ, DS, 2304);
  k_reduce_bias<<<dim3((LQ*DS + 255)/256), 256, 0, stream>>>(scratch, bo, out, LQ*DS, DS, 8);
}

// Round 4
// 386.576 us; speedup vs baseline: 1.1151x; 1.0813x over previous
//
#include <hip/hip_runtime.h>
#include <math.h>

// Problem constants
#define LQ    512
#define DS    384
#define DPAIR 128
#define NH    12
#define NPP   1792   // padded projection width
#define FE    48     // logits feature dim (32 q + 12 pts + 2)
#define TJC   64     // j-chunk for pair kernel
#define NC    8      // number of j-chunks (LQ/TJC)

// ---------------------------------------------------------------- concat W
__global__ void k_concat_w(const float* __restrict__ Wq, const float* __restrict__ Wk,
                           const float* __restrict__ Wv, const float* __restrict__ Wqp,
                           const float* __restrict__ Wkp, const float* __restrict__ Wvp,
                           const float* __restrict__ bq, const float* __restrict__ bk,
                           const float* __restrict__ bv, const float* __restrict__ bqp,
                           const float* __restrict__ bkp, const float* __restrict__ bvp,
                           float* __restrict__ Wcat, float* __restrict__ bcat) {
  int idx = blockIdx.x * 256 + threadIdx.x;
  const int total = DS * NPP;
  if (idx < total) {
    int k = idx / NPP, c = idx % NPP;
    float v = 0.f;
    if (c < 384)       v = Wq[k*384 + c];
    else if (c < 768)  v = Wk[k*384 + c-384];
    else if (c < 1152) v = Wv[k*384 + c-768];
    else if (c < 1296) v = Wqp[k*144 + c-1152];
    else if (c < 1440) v = Wkp[k*144 + c-1296];
    else if (c < 1728) v = Wvp[k*288 + c-1440];
    Wcat[idx] = v;
  } else if (idx < total + NPP) {
    int c = idx - total;
    float v = 0.f;
    if (c < 384)       v = bq[c];
    else if (c < 768)  v = bk[c-384];
    else if (c < 1152) v = bv[c-768];
    else if (c < 1296) v = bqp[c-1152];
    else if (c < 1440) v = bkp[c-1296];
    else if (c < 1728) v = bvp[c-1440];
    bcat[c] = v;
  }
}

// transpose Wpb[k][h] -> WpbT[h][k]
__global__ void k_wpbt(const float* __restrict__ Wpb, float* __restrict__ WpbT) {
  int e = blockIdx.x * 256 + threadIdx.x;
  if (e >= DPAIR * NH) return;
  int k = e / NH, h = e % NH;
  WpbT[h*DPAIR + k] = Wpb[e];
}

// ---------------------------------------------------------------- layernorm
__global__ __launch_bounds__(128) void k_layernorm(const float* __restrict__ x,
                                                   const float* __restrict__ w,
                                                   const float* __restrict__ b,
                                                   float* __restrict__ y) {
  __shared__ float red[128];
  __shared__ float s_mu, s_rstd;
  int i = blockIdx.x, t = threadIdx.x;
  float v0 = x[i*DS + t], v1 = x[i*DS + t + 128], v2 = x[i*DS + t + 256];
  red[t] = v0 + v1 + v2; __syncthreads();
  for (int s = 64; s > 0; s >>= 1) { if (t < s) red[t] += red[t+s]; __syncthreads(); }
  if (t == 0) s_mu = red[0] * (1.f/384.f);
  __syncthreads();
  float mu = s_mu;
  float d0 = v0-mu, d1 = v1-mu, d2 = v2-mu;
  red[t] = d0*d0 + d1*d1 + d2*d2; __syncthreads();
  for (int s = 64; s > 0; s >>= 1) { if (t < s) red[t] += red[t+s]; __syncthreads(); }
  if (t == 0) s_rstd = rsqrtf(red[0] * (1.f/384.f) + 1e-5f);
  __syncthreads();
  float r = s_rstd;
  y[i*DS + t      ] = d0*r*w[t      ] + b[t      ];
  y[i*DS + t + 128] = d1*r*w[t + 128] + b[t + 128];
  y[i*DS + t + 256] = d2*r*w[t + 256] + b[t + 256];
}

// ---------------------------------------------------------------- tiled f32 GEMM (NN)
__global__ __launch_bounds__(256) void k_gemm_nn(const float* __restrict__ A,
                                                 const float* __restrict__ B,
                                                 const float* __restrict__ bias,
                                                 float* __restrict__ C,
                                                 float* __restrict__ Cpart,
                                                 int M, int N, int K) {
  __shared__ float As[16*68];
  __shared__ float Bs[16*68];
  int t = threadIdx.x;
  int mg = t >> 4, ng = t & 15;
  int i0 = blockIdx.y * 64, j0 = blockIdx.x * 64;
  int KS = gridDim.z;
  int kper = K / KS;
  int kbeg = blockIdx.z * kper;
  float acc[4][4] = {};
  for (int k0 = kbeg; k0 < kbeg + kper; k0 += 16) {
    int e = t;
    #pragma unroll
    for (int s = 0; s < 4; s++, e += 256) {
      int m = e >> 4, k = e & 15;
      As[k*68 + m] = A[(size_t)(i0+m)*K + k0 + k];
      int k2 = e >> 6, n = e & 63;
      Bs[k2*68 + n] = B[(size_t)(k0+k2)*N + j0 + n];
    }
    __syncthreads();
    #pragma unroll
    for (int k = 0; k < 16; k++) {
      float4 av = *(const float4*)(As + k*68 + mg*4);
      float4 bv = *(const float4*)(Bs + k*68 + ng*4);
      float a[4] = {av.x, av.y, av.z, av.w};
      float b[4] = {bv.x, bv.y, bv.z, bv.w};
      #pragma unroll
      for (int y = 0; y < 4; y++)
        #pragma unroll
        for (int x = 0; x < 4; x++)
          acc[y][x] = fmaf(a[y], b[x], acc[y][x]);
    }
    __syncthreads();
  }
  if (KS == 1) {
    #pragma unroll
    for (int y = 0; y < 4; y++) {
      int m = i0 + mg*4 + y;
      #pragma unroll
      for (int x = 0; x < 4; x++) {
        int n = j0 + ng*4 + x;
        C[(size_t)m*N + n] = acc[y][x] + bias[n];
      }
    }
  } else {
    float* dst = Cpart + (size_t)blockIdx.z * M * N;
    #pragma unroll
    for (int y = 0; y < 4; y++) {
      int m = i0 + mg*4 + y;
      #pragma unroll
      for (int x = 0; x < 4; x++) {
        int n = j0 + ng*4 + x;
        dst[(size_t)m*N + n] = acc[y][x];
      }
    }
  }
}

__global__ void k_reduce_bias(const float* __restrict__ part, const float* __restrict__ bias,
                              float* __restrict__ out, int MN, int N, int KS) {
  int e = blockIdx.x * 256 + threadIdx.x;
  if (e >= MN) return;
  float s = bias[e % N];
  for (int z = 0; z < KS; z++) s += part[(size_t)z*MN + e];
  out[e] = s;
}

// ---------------------------------------------------------------- rotate points to global frame
__global__ void k_rotate(const float* __restrict__ C1, const float* __restrict__ rot,
                         const float* __restrict__ trans, float* __restrict__ qg,
                         float* __restrict__ kg, float* __restrict__ vg) {
  int idx = blockIdx.x * 256 + threadIdx.x;   // LQ*NH*16
  if (idx >= LQ*NH*16) return;
  int w = idx & 15; int h = (idx >> 4) % NH; int i = idx / (16*NH);
  const float* R = rot + (size_t)i*9;
  const float* tr = trans + (size_t)i*3;
  const float* src; float* dst;
  if (w < 4)      { src = C1 + (size_t)i*NPP + 1152 + h*12 + w*3;     dst = qg + ((size_t)i*NH + h)*12 + w*3; }
  else if (w < 8) { int p = w-4; src = C1 + (size_t)i*NPP + 1296 + h*12 + p*3; dst = kg + ((size_t)i*NH + h)*12 + p*3; }
  else            { int p = w-8; src = C1 + (size_t)i*NPP + 1440 + h*24 + p*3; dst = vg + ((size_t)i*NH + h)*24 + p*3; }
  float x = src[0], y = src[1], z = src[2];
  dst[0] = fmaf(R[0],x, fmaf(R[1],y, fmaf(R[2],z, tr[0])));
  dst[1] = fmaf(R[3],x, fmaf(R[4],y, fmaf(R[5],z, tr[1])));
  dst[2] = fmaf(R[6],x, fmaf(R[7],y, fmaf(R[8],z, tr[2])));
}

// ---------------------------------------------------------------- build 48-dim logits features
__global__ void k_features(const float* __restrict__ C1, const float* __restrict__ qg,
                           const float* __restrict__ kg, const float* __restrict__ gamma,
                           const float* __restrict__ w_c, const float* __restrict__ w_l,
                           float* __restrict__ Af, float* __restrict__ Bf) {
  int idx = blockIdx.x * 256 + threadIdx.x;
  if (idx >= LQ*NH) return;
  int h = idx % NH, i = idx / NH;
  float s  = w_c[0] * rsqrtf(32.f);
  float gp = gamma[h] * w_l[0];
  float* a  = Af + ((size_t)h*LQ + i)*FE;
  float* bb = Bf + ((size_t)h*LQ + i)*FE;
  const float* q = C1 + (size_t)i*NPP + h*32;
  const float* k = C1 + (size_t)i*NPP + 384 + h*32;
  for (int d = 0; d < 32; d++) { a[d] = s*q[d]; bb[d] = k[d]; }
  const float* qp = qg + ((size_t)i*NH + h)*12;
  const float* kp = kg + ((size_t)i*NH + h)*12;
  float sq = 0.f, sk = 0.f;
  for (int d = 0; d < 12; d++) {
    float x = qp[d], y = kp[d];
    a[32+d] = gp*x; bb[32+d] = y;
    sq = fmaf(x,x,sq); sk = fmaf(y,y,sk);
  }
  a[44] = -0.5f*gp*sq; a[45] = 1.f; a[46] = 0.f; a[47] = 0.f;
  bb[44] = 1.f; bb[45] = -0.5f*gp*sk; bb[46] = 0.f; bb[47] = 0.f;
}

// ---------------------------------------------------------------- batched NT GEMM: S[h] = A_h @ B_h^T  (K=48)
__global__ __launch_bounds__(256) void k_logits_nt(const float* __restrict__ Af,
                                                   const float* __restrict__ Bf,
                                                   float* __restrict__ S) {
  __shared__ float As[48*68];
  __shared__ float Bs[48*68];
  int h = blockIdx.z;
  int i0 = blockIdx.y * 64, j0 = blockIdx.x * 64;
  int t = threadIdx.x;
  int mg = t >> 4, ng = t & 15;
  const float* Ah = Af + (size_t)h*LQ*FE;
  const float* Bh = Bf + (size_t)h*LQ*FE;
  for (int e = t; e < 64*48; e += 256) {
    int m = e / 48, k = e % 48;
    As[k*68 + m] = Ah[(size_t)(i0+m)*FE + k];
    Bs[k*68 + m] = Bh[(size_t)(j0+m)*FE + k];
  }
  __syncthreads();
  float acc[4][4] = {};
  #pragma unroll 8
  for (int k = 0; k < 48; k++) {
    float4 av = *(const float4*)(As + k*68 + mg*4);
    float4 bv = *(const float4*)(Bs + k*68 + ng*4);
    float a[4] = {av.x, av.y, av.z, av.w};
    float b[4] = {bv.x, bv.y, bv.z, bv.w};
    #pragma unroll
    for (int y = 0; y < 4; y++)
      #pragma unroll
      for (int x = 0; x < 4; x++)
        acc[y][x] = fmaf(a[y], b[x], acc[y][x]);
  }
  #pragma unroll
  for (int y = 0; y < 4; y++) {
    #pragma unroll
    for (int x = 0; x < 4; x++)
      S[((size_t)h*LQ + i0 + mg*4 + y)*LQ + j0 + ng*4 + x] = acc[y][x];
  }
}

// ---------------------------------------------------------------- pair chunk: bias + chunk softmax + partial pair_out
// grid (i=512, c=8), 256 threads. One 64x128 pair tile per block, loaded once.
// S in: logits (seq+geo). S out: e^{l - m_c} (unnormalized). Also writes
// pairpart[i][c][h][128] and msum[i][c][h][2] = (m_c, s_c).
__global__ __launch_bounds__(256, 4) void k_pair_chunk(
    const float* __restrict__ pair, const float* __restrict__ WpbT,
    const float* __restrict__ bpb, const float* __restrict__ mask,
    float* __restrict__ S, float* __restrict__ pairpart, float* __restrict__ msum) {
  __shared__ float tile[TJC*133];   // 34 KB, padded stride
  __shared__ float wt[NH*TJC];      // 3 KB
  int i = blockIdx.x, c = blockIdx.y, t = threadIdx.x;
  int j0 = c*TJC;

  // stage 64x128 tile, fully coalesced
  const float4* src = (const float4*)(pair + ((size_t)i*LQ + j0)*DPAIR);
  #pragma unroll
  for (int u = 0; u < 8; u++) {
    int e = t + u*256; int row = e >> 5, c4 = e & 31;
    *(float4*)&tile[row*133 + c4*4] = src[e];
  }

  // load logits for this chunk (3 heads per wave)
  int j = t & 63;
  int hg = __builtin_amdgcn_readfirstlane(t >> 6);   // 0..3, wave-uniform
  int h0 = hg*3;
  float l[3];
  #pragma unroll
  for (int q = 0; q < 3; q++)
    l[q] = S[((size_t)(h0+q)*LQ + i)*LQ + j0 + j] + bpb[h0+q];
  bool dead = (mask[i] * mask[j0 + j] <= 0.f);
  __syncthreads();

  // phase A: pair-bias GEMV from LDS tile, weights via scalar loads
  {
    const float* w0p = WpbT + (size_t)(h0+0)*DPAIR;
    const float* w1p = WpbT + (size_t)(h0+1)*DPAIR;
    const float* w2p = WpbT + (size_t)(h0+2)*DPAIR;
    float a0 = 0.f, a1 = 0.f, a2 = 0.f;
    #pragma unroll 8
    for (int k = 0; k < DPAIR; k += 4) {
      float4 pv = *(const float4*)&tile[j*133 + k];
      float4 w0 = *(const float4*)(w0p + k);
      float4 w1 = *(const float4*)(w1p + k);
      float4 w2 = *(const float4*)(w2p + k);
      a0 = fmaf(pv.x,w0.x, fmaf(pv.y,w0.y, fmaf(pv.z,w0.z, fmaf(pv.w,w0.w, a0))));
      a1 = fmaf(pv.x,w1.x, fmaf(pv.y,w1.y, fmaf(pv.z,w1.z, fmaf(pv.w,w1.w, a1))));
      a2 = fmaf(pv.x,w2.x, fmaf(pv.y,w2.y, fmaf(pv.z,w2.z, fmaf(pv.w,w2.w, a2))));
    }
    l[0] += a0; l[1] += a1; l[2] += a2;
    if (dead) { l[0] = -1e9f; l[1] = -1e9f; l[2] = -1e9f; }
  }

  // chunk softmax: per-wave (64 lanes == 64 j) shuffle reduce, 3 heads
  #pragma unroll
  for (int q = 0; q < 3; q++) {
    float m = l[q];
    #pragma unroll
    for (int o = 32; o > 0; o >>= 1) m = fmaxf(m, __shfl_xor(m, o, 64));
    float w = __expf(l[q] - m);
    float sm = w;
    #pragma unroll
    for (int o = 32; o > 0; o >>= 1) sm += __shfl_xor(sm, o, 64);
    wt[(h0+q)*TJC + j] = w;
    S[((size_t)(h0+q)*LQ + i)*LQ + j0 + j] = w;
    if (j == 0) {
      float* dst = msum + (((size_t)i*NC + c)*NH + h0 + q)*2;
      dst[0] = m; dst[1] = sm;
    }
  }
  __syncthreads();

  // phase C: partial pair_out from the same tile
  int dg = t & 31, strip = t >> 5, jb = strip*8;
  float4 pv[8];
  #pragma unroll
  for (int q = 0; q < 8; q++) pv[q] = *(const float4*)&tile[(jb+q)*133 + dg*4];
  float4 acc[NH];
  #pragma unroll
  for (int h = 0; h < NH; h++) acc[h] = make_float4(0.f,0.f,0.f,0.f);
  #pragma unroll
  for (int h = 0; h < NH; h++) {
    float4 w0 = *(const float4*)&wt[h*TJC + jb];
    float4 w1 = *(const float4*)&wt[h*TJC + jb + 4];
    float wq[8] = {w0.x,w0.y,w0.z,w0.w,w1.x,w1.y,w1.z,w1.w};
    float4 a = acc[h];
    #pragma unroll
    for (int q = 0; q < 8; q++) {
      a.x = fmaf(wq[q], pv[q].x, a.x);
      a.y = fmaf(wq[q], pv[q].y, a.y);
      a.z = fmaf(wq[q], pv[q].z, a.z);
      a.w = fmaf(wq[q], pv[q].w, a.w);
    }
    acc[h] = a;
  }
  __syncthreads();   // all tile reads done; reuse tile as reduction scratch

  // reduce 8 strips (two halves of 4) -> pairpart; 256 threads cover all
  // NH*32=384 (h,d) cells via strided loop with 2 accumulators per thread.
  float4* red4 = (float4*)tile;    // need 4*12*32 = 1536 float4 <= 2128 cap
  float4 tot[2];
  tot[0] = make_float4(0.f,0.f,0.f,0.f);
  tot[1] = make_float4(0.f,0.f,0.f,0.f);
  #pragma unroll
  for (int half = 0; half < 2; half++) {
    if ((strip >> 2) == half) {
      #pragma unroll
      for (int h = 0; h < NH; h++)
        red4[(((strip & 3)*NH) + h)*32 + dg] = acc[h];
    }
    __syncthreads();
    for (int e = t, u = 0; e < NH*32; e += 256, u++) {
      int rh = e >> 5, rd = e & 31;
      #pragma unroll
      for (int s4 = 0; s4 < 4; s4++) {
        float4 v = red4[((s4*NH) + rh)*32 + rd];
        tot[u].x += v.x; tot[u].y += v.y; tot[u].z += v.z; tot[u].w += v.w;
      }
    }
    __syncthreads();
  }
  for (int e = t, u = 0; e < NH*32; e += 256, u++) {
    int rh = e >> 5, rd = e & 31;
    *(float4*)&pairpart[(((size_t)i*NC + c)*NH + rh)*DPAIR + rd*4] = tot[u];
  }
}

// ---------------------------------------------------------------- merge chunks: global softmax scale + pair_out + S normalize
__global__ __launch_bounds__(512) void k_merge(
    const float* __restrict__ msum, const float* __restrict__ pairpart,
    float* __restrict__ S, float* __restrict__ comb) {
  __shared__ float scs[NH*NC];
  int i = blockIdx.x, t = threadIdx.x;
  if (t < NH) {
    float m = -3.0e38f;
    float mc[NC], sc_[NC];
    #pragma unroll
    for (int c = 0; c < NC; c++) {
      const float* p = msum + (((size_t)i*NC + c)*NH + t)*2;
      mc[c] = p[0]; sc_[c] = p[1];
      m = fmaxf(m, mc[c]);
    }
    float s = 0.f;
    #pragma unroll
    for (int c = 0; c < NC; c++) s += sc_[c] * __expf(mc[c] - m);
    float inv = 1.f / s;
    #pragma unroll
    for (int c = 0; c < NC; c++) scs[t*NC + c] = __expf(mc[c] - m) * inv;
  }
  __syncthreads();
  // pair_out combine
  if (t < NH*32) {
    int h = t >> 5, d = t & 31;
    float4 tot = make_float4(0.f,0.f,0.f,0.f);
    #pragma unroll
    for (int c = 0; c < NC; c++) {
      float sc = scs[h*NC + c];
      float4 v = *(const float4*)&pairpart[(((size_t)i*NC + c)*NH + h)*DPAIR + d*4];
      tot.x = fmaf(v.x, sc, tot.x); tot.y = fmaf(v.y, sc, tot.y);
      tot.z = fmaf(v.z, sc, tot.z); tot.w = fmaf(v.w, sc, tot.w);
    }
    *(float4*)&comb[(size_t)i*2304 + 768 + h*DPAIR + d*4] = tot;
  }
  // normalize S in place
  for (int e = t; e < NH*LQ; e += 512) {
    int h = e >> 9, j = e & 511;
    size_t idx = ((size_t)h*LQ + i)*LQ + j;
    S[idx] *= scs[h*NC + (j >> 6)];
  }
}

// ---------------------------------------------------------------- attn @ [v | vg] per head, split-K=4 -> psum
__global__ __launch_bounds__(256) void k_attn_v(const float* __restrict__ attn,
                                                const float* __restrict__ C1,
                                                const float* __restrict__ vg,
                                                float* __restrict__ psum) {
  __shared__ float As[64*68];   // [j][m] (transposed)
  __shared__ float Vs[64*68];   // [j][n], n<56 valid
  int i0 = blockIdx.x * 64;
  int h = blockIdx.y;
  int z = blockIdx.z;
  int t = threadIdx.x;
  int mg = t >> 4, ng = t & 15;
  float acc[4][4] = {};
  for (int k0 = z*128; k0 < z*128 + 128; k0 += 64) {
    __syncthreads();
    for (int e = t; e < 64*64; e += 256) {
      int m = e >> 6, j = e & 63;
      As[j*68 + m] = attn[((size_t)h*LQ + i0 + m)*LQ + k0 + j];
    }
    for (int e = t; e < 64*64; e += 256) {
      int j = e >> 6, c = e & 63;
      float v = 0.f;
      if (c < 32)      v = C1[(size_t)(k0+j)*NPP + 768 + h*32 + c];
      else if (c < 56) v = vg[((size_t)(k0+j)*NH + h)*24 + (c-32)];
      Vs[j*68 + c] = v;
    }
    __syncthreads();
    #pragma unroll 4
    for (int j = 0; j < 64; j++) {
      float4 av = *(const float4*)(As + j*68 + mg*4);
      float4 bv = *(const float4*)(Vs + j*68 + ng*4);
      float a[4] = {av.x, av.y, av.z, av.w};
      float b[4] = {bv.x, bv.y, bv.z, bv.w};
      #pragma unroll
      for (int y = 0; y < 4; y++)
        #pragma unroll
        for (int x = 0; x < 4; x++)
          acc[y][x] = fmaf(a[y], b[x], acc[y][x]);
    }
  }
  #pragma unroll
  for (int y = 0; y < 4; y++) {
    int i = i0 + mg*4 + y;
    #pragma unroll
    for (int x = 0; x < 4; x++) {
      int n = ng*4 + x;
      psum[(((size_t)z*LQ + i)*NH + h)*64 + n] = acc[y][x];
    }
  }
}

__global__ void k_av_reduce(const float* __restrict__ psum, float* __restrict__ comb,
                            float* __restrict__ pts) {
  int e = blockIdx.x * 256 + threadIdx.x;   // LQ*NH*56
  if (e >= LQ*NH*56) return;
  int n = e % 56; int ih = e / 56; int h = ih % NH; int i = ih / NH;
  size_t base = ((size_t)i*NH + h)*64 + n;
  float s = 0.f;
  for (int z = 0; z < 4; z++) s += psum[(size_t)z*LQ*NH*64 + base];
  if (n < 32) comb[(size_t)i*2304 + h*32 + n] = s;
  else        pts[((size_t)i*NH + h)*24 + (n-32)] = s;
}

// ---------------------------------------------------------------- point features: local frame + norm
__global__ void k_pts_feat(const float* __restrict__ pts, const float* __restrict__ rot,
                           const float* __restrict__ trans, float* __restrict__ comb) {
  int idx = blockIdx.x * 256 + threadIdx.x;   // LQ*NH*8
  if (idx >= LQ*NH*8) return;
  int p = idx & 7; int h = (idx >> 3) % NH; int i = idx / (8*NH);
  const float* R = rot + (size_t)i*9;
  const float* tr = trans + (size_t)i*3;
  const float* pt = pts + ((size_t)i*NH + h)*24 + p*3;
  float x = pt[0]-tr[0], y = pt[1]-tr[1], z = pt[2]-tr[2];
  float lx = fmaf(R[0],x, fmaf(R[3],y, R[6]*z));
  float ly = fmaf(R[1],x, fmaf(R[4],y, R[7]*z));
  float lz = fmaf(R[2],x, fmaf(R[5],y, R[8]*z));
  float nrm = sqrtf(fmaf(lx,lx, fmaf(ly,ly, lz*lz)));
  float* dst = comb + (size_t)i*2304 + 384 + (h*8 + p)*4;
  dst[0] = nrm; dst[1] = lx; dst[2] = ly; dst[3] = lz;
}

// ================================================================ launcher
extern "C" void kernel_launch(void* const* d_in, const int* in_sizes, int n_in,
                              void* d_out, int out_size, void* d_ws, size_t ws_size,
                              hipStream_t stream) {
  const float* single = (const float*)d_in[0];
  const float* pair   = (const float*)d_in[1];
  const float* rot    = (const float*)d_in[2];
  const float* trans  = (const float*)d_in[3];
  const float* mask   = (const float*)d_in[4];
  const float* ln_w   = (const float*)d_in[5];
  const float* ln_b   = (const float*)d_in[6];
  const float* Wq     = (const float*)d_in[7];
  const float* bq     = (const float*)d_in[8];
  const float* Wk     = (const float*)d_in[9];
  const float* bk     = (const float*)d_in[10];
  const float* Wv     = (const float*)d_in[11];
  const float* bv     = (const float*)d_in[12];
  const float* Wqp    = (const float*)d_in[13];
  const float* bqp    = (const float*)d_in[14];
  const float* Wkp    = (const float*)d_in[15];
  const float* bkp    = (const float*)d_in[16];
  const float* Wvp    = (const float*)d_in[17];
  const float* bvp    = (const float*)d_in[18];
  const float* Wpb    = (const float*)d_in[19];
  const float* bpb    = (const float*)d_in[20];
  const float* Wo     = (const float*)d_in[21];
  const float* bo     = (const float*)d_in[22];
  const float* w_c    = (const float*)d_in[23];
  const float* w_l    = (const float*)d_in[24];
  const float* gamma  = (const float*)d_in[25];
  float* out = (float*)d_out;

  float* p = (float*)d_ws;
  auto alloc = [&](size_t n) { float* r = p; p += n; return r; };
  float* Wcat    = alloc((size_t)DS*NPP);
  float* bcat    = alloc(NPP);
  float* WpbT    = alloc((size_t)NH*DPAIR);
  float* sn      = alloc((size_t)LQ*DS);
  float* C1      = alloc((size_t)LQ*NPP);
  float* qg      = alloc((size_t)LQ*NH*12);
  float* kg      = alloc((size_t)LQ*NH*12);
  float* vgb     = alloc((size_t)LQ*NH*24);
  float* Af      = alloc((size_t)NH*LQ*FE);
  float* Bf      = alloc((size_t)NH*LQ*FE);
  float* S       = alloc((size_t)NH*LQ*LQ);
  float* pairpart= alloc((size_t)LQ*NC*NH*DPAIR);
  float* msum    = alloc((size_t)LQ*NC*NH*2);
  float* comb    = alloc((size_t)LQ*2304);
  float* pts     = alloc((size_t)LQ*NH*24);
  float* scratch = alloc((size_t)8*LQ*DS);   // psum / out-GEMM partials

  k_concat_w<<<dim3((DS*NPP + NPP + 255)/256), 256, 0, stream>>>(
      Wq, Wk, Wv, Wqp, Wkp, Wvp, bq, bk, bv, bqp, bkp, bvp, Wcat, bcat);
  k_wpbt<<<dim3((DPAIR*NH + 255)/256), 256, 0, stream>>>(Wpb, WpbT);
  k_layernorm<<<dim3(LQ), 128, 0, stream>>>(single, ln_w, ln_b, sn);
  k_gemm_nn<<<dim3(NPP/64, LQ/64, 1), 256, 0, stream>>>(sn, Wcat, bcat, C1, nullptr, LQ, NPP, DS);
  k_rotate<<<dim3((LQ*NH*16 + 255)/256), 256, 0, stream>>>(C1, rot, trans, qg, kg, vgb);
  k_features<<<dim3((LQ*NH + 255)/256), 256, 0, stream>>>(C1, qg, kg, gamma, w_c, w_l, Af, Bf);
  k_logits_nt<<<dim3(LQ/64, LQ/64, NH), 256, 0, stream>>>(Af, Bf, S);
  k_pair_chunk<<<dim3(LQ, NC), 256, 0, stream>>>(pair, WpbT, bpb, mask, S, pairpart, msum);
  k_merge<<<dim3(LQ), 512, 0, stream>>>(msum, pairpart, S, comb);
  k_attn_v<<<dim3(LQ/64, NH, 4), 256, 0, stream>>>(S, C1, vgb, scratch);
  k_av_reduce<<<dim3((LQ*NH*56 + 255)/256), 256, 0, stream>>>(scratch, comb, pts);
  k_pts_feat<<<dim3((LQ*NH*8 + 255)/256), 256, 0, stream>>>(pts, rot, trans, comb);
  k_gemm_nn<<<dim3(DS/64, LQ/64, 8), 256, 0, stream>>>(comb, Wo, bo, nullptr, scratch, LQ, DS, 2304);
  k_reduce_bias<<<dim3((LQ*DS + 255)/256), 256, 0, stream>>>(scratch, bo, out, LQ*DS, DS, 8);
}

// Round 5
// 379.274 us; speedup vs baseline: 1.1365x; 1.0193x over previous
//
#include <hip/hip_runtime.h>
#include <math.h>

// Problem constants
#define LQ    512
#define DS    384
#define DPAIR 128
#define NH    12
#define NPP   1792   // padded projection width
#define FE    48     // logits feature dim (32 q + 12 pts + 2)
#define TJC   64     // j-chunk for pair kernel
#define NC    8      // number of j-chunks (LQ/TJC)

// ---------------------------------------------------------------- concat W (+ WpbT transpose folded in)
__global__ void k_concat_w(const float* __restrict__ Wq, const float* __restrict__ Wk,
                           const float* __restrict__ Wv, const float* __restrict__ Wqp,
                           const float* __restrict__ Wkp, const float* __restrict__ Wvp,
                           const float* __restrict__ bq, const float* __restrict__ bk,
                           const float* __restrict__ bv, const float* __restrict__ bqp,
                           const float* __restrict__ bkp, const float* __restrict__ bvp,
                           const float* __restrict__ Wpb,
                           float* __restrict__ Wcat, float* __restrict__ bcat,
                           float* __restrict__ WpbT) {
  int idx = blockIdx.x * 256 + threadIdx.x;
  const int total = DS * NPP;
  if (idx < total) {
    int k = idx / NPP, c = idx % NPP;
    float v = 0.f;
    if (c < 384)       v = Wq[k*384 + c];
    else if (c < 768)  v = Wk[k*384 + c-384];
    else if (c < 1152) v = Wv[k*384 + c-768];
    else if (c < 1296) v = Wqp[k*144 + c-1152];
    else if (c < 1440) v = Wkp[k*144 + c-1296];
    else if (c < 1728) v = Wvp[k*288 + c-1440];
    Wcat[idx] = v;
  } else if (idx < total + NPP) {
    int c = idx - total;
    float v = 0.f;
    if (c < 384)       v = bq[c];
    else if (c < 768)  v = bk[c-384];
    else if (c < 1152) v = bv[c-768];
    else if (c < 1296) v = bqp[c-1152];
    else if (c < 1440) v = bkp[c-1296];
    else if (c < 1728) v = bvp[c-1440];
    bcat[c] = v;
  } else if (idx < total + NPP + DPAIR*NH) {
    int e = idx - total - NPP;
    int k = e / NH, h = e % NH;
    WpbT[h*DPAIR + k] = Wpb[e];
  }
}

// ---------------------------------------------------------------- layernorm
__global__ __launch_bounds__(128) void k_layernorm(const float* __restrict__ x,
                                                   const float* __restrict__ w,
                                                   const float* __restrict__ b,
                                                   float* __restrict__ y) {
  __shared__ float red[128];
  __shared__ float s_mu, s_rstd;
  int i = blockIdx.x, t = threadIdx.x;
  float v0 = x[i*DS + t], v1 = x[i*DS + t + 128], v2 = x[i*DS + t + 256];
  red[t] = v0 + v1 + v2; __syncthreads();
  for (int s = 64; s > 0; s >>= 1) { if (t < s) red[t] += red[t+s]; __syncthreads(); }
  if (t == 0) s_mu = red[0] * (1.f/384.f);
  __syncthreads();
  float mu = s_mu;
  float d0 = v0-mu, d1 = v1-mu, d2 = v2-mu;
  red[t] = d0*d0 + d1*d1 + d2*d2; __syncthreads();
  for (int s = 64; s > 0; s >>= 1) { if (t < s) red[t] += red[t+s]; __syncthreads(); }
  if (t == 0) s_rstd = rsqrtf(red[0] * (1.f/384.f) + 1e-5f);
  __syncthreads();
  float r = s_rstd;
  y[i*DS + t      ] = d0*r*w[t      ] + b[t      ];
  y[i*DS + t + 128] = d1*r*w[t + 128] + b[t + 128];
  y[i*DS + t + 256] = d2*r*w[t + 256] + b[t + 256];
}

// ---------------------------------------------------------------- tiled f32 GEMM (NN), optional split-K
__global__ __launch_bounds__(256) void k_gemm_nn(const float* __restrict__ A,
                                                 const float* __restrict__ B,
                                                 const float* __restrict__ bias,
                                                 float* __restrict__ C,
                                                 float* __restrict__ Cpart,
                                                 int M, int N, int K) {
  __shared__ float As[16*68];
  __shared__ float Bs[16*68];
  int t = threadIdx.x;
  int mg = t >> 4, ng = t & 15;
  int i0 = blockIdx.y * 64, j0 = blockIdx.x * 64;
  int KS = gridDim.z;
  int kper = K / KS;
  int kbeg = blockIdx.z * kper;
  float acc[4][4] = {};
  for (int k0 = kbeg; k0 < kbeg + kper; k0 += 16) {
    int e = t;
    #pragma unroll
    for (int s = 0; s < 4; s++, e += 256) {
      int m = e >> 4, k = e & 15;
      As[k*68 + m] = A[(size_t)(i0+m)*K + k0 + k];
      int k2 = e >> 6, n = e & 63;
      Bs[k2*68 + n] = B[(size_t)(k0+k2)*N + j0 + n];
    }
    __syncthreads();
    #pragma unroll
    for (int k = 0; k < 16; k++) {
      float4 av = *(const float4*)(As + k*68 + mg*4);
      float4 bv = *(const float4*)(Bs + k*68 + ng*4);
      float a[4] = {av.x, av.y, av.z, av.w};
      float b[4] = {bv.x, bv.y, bv.z, bv.w};
      #pragma unroll
      for (int y = 0; y < 4; y++)
        #pragma unroll
        for (int x = 0; x < 4; x++)
          acc[y][x] = fmaf(a[y], b[x], acc[y][x]);
    }
    __syncthreads();
  }
  if (KS == 1) {
    #pragma unroll
    for (int y = 0; y < 4; y++) {
      int m = i0 + mg*4 + y;
      #pragma unroll
      for (int x = 0; x < 4; x++) {
        int n = j0 + ng*4 + x;
        C[(size_t)m*N + n] = acc[y][x] + bias[n];
      }
    }
  } else {
    float* dst = Cpart + (size_t)blockIdx.z * M * N;
    #pragma unroll
    for (int y = 0; y < 4; y++) {
      int m = i0 + mg*4 + y;
      #pragma unroll
      for (int x = 0; x < 4; x++) {
        int n = j0 + ng*4 + x;
        dst[(size_t)m*N + n] = acc[y][x];
      }
    }
  }
}

__global__ void k_reduce_bias(const float* __restrict__ part, const float* __restrict__ bias,
                              float* __restrict__ out, int MN, int N, int KS) {
  int e = blockIdx.x * 256 + threadIdx.x;
  if (e >= MN) return;
  float s = bias[e % N];
  for (int z = 0; z < KS; z++) s += part[(size_t)z*MN + e];
  out[e] = s;
}

// ---------------------------------------------------------------- fused rotate + feature build
// one thread per (i,h): rotates q/k/v points to global frame, writes vgb and the
// 48-dim logit features Af/Bf.
__global__ void k_rotfeat(const float* __restrict__ C1, const float* __restrict__ rot,
                          const float* __restrict__ trans, const float* __restrict__ gamma,
                          const float* __restrict__ w_c, const float* __restrict__ w_l,
                          float* __restrict__ Af, float* __restrict__ Bf,
                          float* __restrict__ vgb) {
  int idx = blockIdx.x * 256 + threadIdx.x;
  if (idx >= LQ*NH) return;
  int h = idx % NH, i = idx / NH;
  float R[9], tr[3];
  #pragma unroll
  for (int r = 0; r < 9; r++) R[r] = rot[(size_t)i*9 + r];
  #pragma unroll
  for (int r = 0; r < 3; r++) tr[r] = trans[(size_t)i*3 + r];

  float s  = w_c[0] * rsqrtf(32.f);
  float gp = gamma[h] * w_l[0];
  float* a  = Af + ((size_t)h*LQ + i)*FE;
  float* bb = Bf + ((size_t)h*LQ + i)*FE;
  const float* q = C1 + (size_t)i*NPP + h*32;
  const float* k = C1 + (size_t)i*NPP + 384 + h*32;
  #pragma unroll 8
  for (int d = 0; d < 32; d++) { a[d] = s*q[d]; bb[d] = k[d]; }

  const float* qp = C1 + (size_t)i*NPP + 1152 + h*12;
  const float* kp = C1 + (size_t)i*NPP + 1296 + h*12;
  float sq = 0.f, sk = 0.f;
  #pragma unroll
  for (int p = 0; p < 4; p++) {
    float x = qp[p*3], y = qp[p*3+1], z = qp[p*3+2];
    #pragma unroll
    for (int r = 0; r < 3; r++) {
      float g = fmaf(R[r*3],x, fmaf(R[r*3+1],y, fmaf(R[r*3+2],z, tr[r])));
      a[32 + p*3 + r] = gp*g;
      sq = fmaf(g,g,sq);
    }
    float xk = kp[p*3], yk = kp[p*3+1], zk = kp[p*3+2];
    #pragma unroll
    for (int r = 0; r < 3; r++) {
      float g = fmaf(R[r*3],xk, fmaf(R[r*3+1],yk, fmaf(R[r*3+2],zk, tr[r])));
      bb[32 + p*3 + r] = g;
      sk = fmaf(g,g,sk);
    }
  }
  a[44] = -0.5f*gp*sq; a[45] = 1.f; a[46] = 0.f; a[47] = 0.f;
  bb[44] = 1.f; bb[45] = -0.5f*gp*sk; bb[46] = 0.f; bb[47] = 0.f;

  const float* vp = C1 + (size_t)i*NPP + 1440 + h*24;
  float* vd = vgb + ((size_t)i*NH + h)*24;
  #pragma unroll
  for (int p = 0; p < 8; p++) {
    float x = vp[p*3], y = vp[p*3+1], z = vp[p*3+2];
    #pragma unroll
    for (int r = 0; r < 3; r++)
      vd[p*3 + r] = fmaf(R[r*3],x, fmaf(R[r*3+1],y, fmaf(R[r*3+2],z, tr[r])));
  }
}

// ---------------------------------------------------------------- batched NT GEMM: S[h] = A_h @ B_h^T  (K=48)
__global__ __launch_bounds__(256) void k_logits_nt(const float* __restrict__ Af,
                                                   const float* __restrict__ Bf,
                                                   float* __restrict__ S) {
  __shared__ float As[48*68];
  __shared__ float Bs[48*68];
  int h = blockIdx.z;
  int i0 = blockIdx.y * 64, j0 = blockIdx.x * 64;
  int t = threadIdx.x;
  int mg = t >> 4, ng = t & 15;
  const float* Ah = Af + (size_t)h*LQ*FE;
  const float* Bh = Bf + (size_t)h*LQ*FE;
  for (int e = t; e < 64*48; e += 256) {
    int m = e / 48, k = e % 48;
    As[k*68 + m] = Ah[(size_t)(i0+m)*FE + k];
    Bs[k*68 + m] = Bh[(size_t)(j0+m)*FE + k];
  }
  __syncthreads();
  float acc[4][4] = {};
  #pragma unroll 8
  for (int k = 0; k < 48; k++) {
    float4 av = *(const float4*)(As + k*68 + mg*4);
    float4 bv = *(const float4*)(Bs + k*68 + ng*4);
    float a[4] = {av.x, av.y, av.z, av.w};
    float b[4] = {bv.x, bv.y, bv.z, bv.w};
    #pragma unroll
    for (int y = 0; y < 4; y++)
      #pragma unroll
      for (int x = 0; x < 4; x++)
        acc[y][x] = fmaf(a[y], b[x], acc[y][x]);
  }
  #pragma unroll
  for (int y = 0; y < 4; y++) {
    #pragma unroll
    for (int x = 0; x < 4; x++)
      S[((size_t)h*LQ + i0 + mg*4 + y)*LQ + j0 + ng*4 + x] = acc[y][x];
  }
}

// ---------------------------------------------------------------- pair chunk: bias + chunk softmax + partial pair_out
// grid (i=512, c=8), 256 threads. One 64x128 pair tile per block, loaded once.
// S out: e^{l - m_c} (unnormalized). pairpart[i][c][h][128], msum[i][c][h][2].
__global__ __launch_bounds__(256, 2) void k_pair_chunk(
    const float* __restrict__ pair, const float* __restrict__ WpbT,
    const float* __restrict__ bpb, const float* __restrict__ mask,
    float* __restrict__ S, float* __restrict__ pairpart, float* __restrict__ msum) {
  __shared__ float tile[TJC*133];   // 34 KB, padded stride
  __shared__ float wt[NH*TJC];      // 3 KB
  int i = blockIdx.x, c = blockIdx.y, t = threadIdx.x;
  int j0 = c*TJC;

  // stage 64x128 tile, fully coalesced
  const float4* src = (const float4*)(pair + ((size_t)i*LQ + j0)*DPAIR);
  #pragma unroll
  for (int u = 0; u < 8; u++) {
    int e = t + u*256; int row = e >> 5, c4 = e & 31;
    *(float4*)&tile[row*133 + c4*4] = src[e];
  }

  // load logits for this chunk (3 heads per wave)
  int j = t & 63;
  int hg = __builtin_amdgcn_readfirstlane(t >> 6);   // 0..3, wave-uniform
  int h0 = hg*3;
  float l[3];
  #pragma unroll
  for (int q = 0; q < 3; q++)
    l[q] = S[((size_t)(h0+q)*LQ + i)*LQ + j0 + j] + bpb[h0+q];
  bool dead = (mask[i] * mask[j0 + j] <= 0.f);
  __syncthreads();

  // phase A: pair-bias GEMV from LDS tile, weights wave-uniform
  {
    const float* w0p = WpbT + (size_t)(h0+0)*DPAIR;
    const float* w1p = WpbT + (size_t)(h0+1)*DPAIR;
    const float* w2p = WpbT + (size_t)(h0+2)*DPAIR;
    float a0 = 0.f, a1 = 0.f, a2 = 0.f;
    #pragma unroll 8
    for (int k = 0; k < DPAIR; k += 4) {
      float4 pv = *(const float4*)&tile[j*133 + k];
      float4 w0 = *(const float4*)(w0p + k);
      float4 w1 = *(const float4*)(w1p + k);
      float4 w2 = *(const float4*)(w2p + k);
      a0 = fmaf(pv.x,w0.x, fmaf(pv.y,w0.y, fmaf(pv.z,w0.z, fmaf(pv.w,w0.w, a0))));
      a1 = fmaf(pv.x,w1.x, fmaf(pv.y,w1.y, fmaf(pv.z,w1.z, fmaf(pv.w,w1.w, a1))));
      a2 = fmaf(pv.x,w2.x, fmaf(pv.y,w2.y, fmaf(pv.z,w2.z, fmaf(pv.w,w2.w, a2))));
    }
    l[0] += a0; l[1] += a1; l[2] += a2;
    if (dead) { l[0] = -1e9f; l[1] = -1e9f; l[2] = -1e9f; }
  }

  // chunk softmax: per-wave shuffle reduce, 3 heads
  #pragma unroll
  for (int q = 0; q < 3; q++) {
    float m = l[q];
    #pragma unroll
    for (int o = 32; o > 0; o >>= 1) m = fmaxf(m, __shfl_xor(m, o, 64));
    float w = __expf(l[q] - m);
    float sm = w;
    #pragma unroll
    for (int o = 32; o > 0; o >>= 1) sm += __shfl_xor(sm, o, 64);
    wt[(h0+q)*TJC + j] = w;
    S[((size_t)(h0+q)*LQ + i)*LQ + j0 + j] = w;
    if (j == 0) {
      float* dst = msum + (((size_t)i*NC + c)*NH + h0 + q)*2;
      dst[0] = m; dst[1] = sm;
    }
  }
  __syncthreads();

  // phase C: partial pair_out from the same tile (tile reads amortized over 12 heads)
  int dg = t & 31, strip = t >> 5, jb = strip*8;
  float4 pv[8];
  #pragma unroll
  for (int q = 0; q < 8; q++) pv[q] = *(const float4*)&tile[(jb+q)*133 + dg*4];
  float4 acc[NH];
  #pragma unroll
  for (int h = 0; h < NH; h++) acc[h] = make_float4(0.f,0.f,0.f,0.f);
  #pragma unroll
  for (int h = 0; h < NH; h++) {
    float4 w0 = *(const float4*)&wt[h*TJC + jb];
    float4 w1 = *(const float4*)&wt[h*TJC + jb + 4];
    float wq[8] = {w0.x,w0.y,w0.z,w0.w,w1.x,w1.y,w1.z,w1.w};
    float4 a = acc[h];
    #pragma unroll
    for (int q = 0; q < 8; q++) {
      a.x = fmaf(wq[q], pv[q].x, a.x);
      a.y = fmaf(wq[q], pv[q].y, a.y);
      a.z = fmaf(wq[q], pv[q].z, a.z);
      a.w = fmaf(wq[q], pv[q].w, a.w);
    }
    acc[h] = a;
  }
  __syncthreads();   // all tile reads done; reuse tile as reduction scratch

  // reduce 8 strips (two halves of 4) -> pairpart
  float4* red4 = (float4*)tile;    // 4*12*32 = 1536 float4 <= 2128 cap
  float4 tot[2];
  tot[0] = make_float4(0.f,0.f,0.f,0.f);
  tot[1] = make_float4(0.f,0.f,0.f,0.f);
  #pragma unroll
  for (int half = 0; half < 2; half++) {
    if ((strip >> 2) == half) {
      #pragma unroll
      for (int h = 0; h < NH; h++)
        red4[(((strip & 3)*NH) + h)*32 + dg] = acc[h];
    }
    __syncthreads();
    for (int e = t, u = 0; e < NH*32; e += 256, u++) {
      int rh = e >> 5, rd = e & 31;
      #pragma unroll
      for (int s4 = 0; s4 < 4; s4++) {
        float4 v = red4[((s4*NH) + rh)*32 + rd];
        tot[u].x += v.x; tot[u].y += v.y; tot[u].z += v.z; tot[u].w += v.w;
      }
    }
    __syncthreads();
  }
  for (int e = t, u = 0; e < NH*32; e += 256, u++) {
    int rh = e >> 5, rd = e & 31;
    *(float4*)&pairpart[(((size_t)i*NC + c)*NH + rh)*DPAIR + rd*4] = tot[u];
  }
}

// ---------------------------------------------------------------- per-chunk softmax scales + pair_out combine
// scs[i][h][c] = e^{m_c - m} / s_total; attn_v applies it to S on the fly.
__global__ __launch_bounds__(384) void k_scs_pairout(
    const float* __restrict__ msum, const float* __restrict__ pairpart,
    float* __restrict__ scs_g, float* __restrict__ comb) {
  __shared__ float scs[NH*NC];
  int i = blockIdx.x, t = threadIdx.x;
  if (t < NH) {
    float m = -3.0e38f;
    float mc[NC], sc_[NC];
    #pragma unroll
    for (int c = 0; c < NC; c++) {
      const float* p = msum + (((size_t)i*NC + c)*NH + t)*2;
      mc[c] = p[0]; sc_[c] = p[1];
      m = fmaxf(m, mc[c]);
    }
    float s = 0.f;
    #pragma unroll
    for (int c = 0; c < NC; c++) s += sc_[c] * __expf(mc[c] - m);
    float inv = 1.f / s;
    #pragma unroll
    for (int c = 0; c < NC; c++) {
      float v = __expf(mc[c] - m) * inv;
      scs[t*NC + c] = v;
      scs_g[((size_t)i*NH + t)*NC + c] = v;
    }
  }
  __syncthreads();
  int h = t >> 5, d = t & 31;
  float4 tot = make_float4(0.f,0.f,0.f,0.f);
  #pragma unroll
  for (int c = 0; c < NC; c++) {
    float sc = scs[h*NC + c];
    float4 v = *(const float4*)&pairpart[(((size_t)i*NC + c)*NH + h)*DPAIR + d*4];
    tot.x = fmaf(v.x, sc, tot.x); tot.y = fmaf(v.y, sc, tot.y);
    tot.z = fmaf(v.z, sc, tot.z); tot.w = fmaf(v.w, sc, tot.w);
  }
  *(float4*)&comb[(size_t)i*2304 + 768 + h*DPAIR + d*4] = tot;
}

// ---------------------------------------------------------------- attn @ [v | vg] per head, split-K=4 -> psum
// S holds unnormalized e^{l-m_c}; scale scs[i][h][c] applied during As staging
// (wave-uniform index -> scalar load).
__global__ __launch_bounds__(256) void k_attn_v(const float* __restrict__ attn,
                                                const float* __restrict__ C1,
                                                const float* __restrict__ vg,
                                                const float* __restrict__ scs,
                                                float* __restrict__ psum) {
  __shared__ float As[64*68];   // [j][m] (transposed)
  __shared__ float Vs[64*68];   // [j][n], n<56 valid
  int i0 = blockIdx.x * 64;
  int h = blockIdx.y;
  int z = blockIdx.z;
  int t = threadIdx.x;
  int mg = t >> 4, ng = t & 15;
  float acc[4][4] = {};
  for (int k0 = z*128; k0 < z*128 + 128; k0 += 64) {
    int c = k0 >> 6;
    __syncthreads();
    for (int e = t; e < 64*64; e += 256) {
      int m = e >> 6, j = e & 63;
      float sc = scs[((size_t)(i0+m)*NH + h)*NC + c];
      As[j*68 + m] = attn[((size_t)h*LQ + i0 + m)*LQ + k0 + j] * sc;
    }
    for (int e = t; e < 64*64; e += 256) {
      int j = e >> 6, cc = e & 63;
      float v = 0.f;
      if (cc < 32)      v = C1[(size_t)(k0+j)*NPP + 768 + h*32 + cc];
      else if (cc < 56) v = vg[((size_t)(k0+j)*NH + h)*24 + (cc-32)];
      Vs[j*68 + cc] = v;
    }
    __syncthreads();
    #pragma unroll 4
    for (int j = 0; j < 64; j++) {
      float4 av = *(const float4*)(As + j*68 + mg*4);
      float4 bv = *(const float4*)(Vs + j*68 + ng*4);
      float a[4] = {av.x, av.y, av.z, av.w};
      float b[4] = {bv.x, bv.y, bv.z, bv.w};
      #pragma unroll
      for (int y = 0; y < 4; y++)
        #pragma unroll
        for (int x = 0; x < 4; x++)
          acc[y][x] = fmaf(a[y], b[x], acc[y][x]);
    }
  }
  #pragma unroll
  for (int y = 0; y < 4; y++) {
    int i = i0 + mg*4 + y;
    #pragma unroll
    for (int x = 0; x < 4; x++) {
      int n = ng*4 + x;
      psum[(((size_t)z*LQ + i)*NH + h)*64 + n] = acc[y][x];
    }
  }
}

// ---------------------------------------------------------------- fused av_reduce + pts_feat
// idx over LQ*NH*40: w<32 -> v path; w in [32,40) -> point p = w-32
__global__ void k_avpts(const float* __restrict__ psum, const float* __restrict__ rot,
                        const float* __restrict__ trans, float* __restrict__ comb) {
  int idx = blockIdx.x * 256 + threadIdx.x;
  if (idx >= LQ*NH*40) return;
  int w = idx % 40; int ih = idx / 40; int h = ih % NH; int i = ih / NH;
  size_t base = ((size_t)i*NH + h)*64;
  if (w < 32) {
    float s = 0.f;
    for (int z = 0; z < 4; z++) s += psum[(size_t)z*LQ*NH*64 + base + w];
    comb[(size_t)i*2304 + h*32 + w] = s;
  } else {
    int p = w - 32;
    float g[3];
    #pragma unroll
    for (int r = 0; r < 3; r++) {
      int n = 32 + p*3 + r;
      float s = 0.f;
      for (int z = 0; z < 4; z++) s += psum[(size_t)z*LQ*NH*64 + base + n];
      g[r] = s;
    }
    const float* R = rot + (size_t)i*9;
    const float* tr = trans + (size_t)i*3;
    float x = g[0]-tr[0], y = g[1]-tr[1], z = g[2]-tr[2];
    float lx = fmaf(R[0],x, fmaf(R[3],y, R[6]*z));
    float ly = fmaf(R[1],x, fmaf(R[4],y, R[7]*z));
    float lz = fmaf(R[2],x, fmaf(R[5],y, R[8]*z));
    float nrm = sqrtf(fmaf(lx,lx, fmaf(ly,ly, lz*lz)));
    float* dst = comb + (size_t)i*2304 + 384 + (h*8 + p)*4;
    dst[0] = nrm; dst[1] = lx; dst[2] = ly; dst[3] = lz;
  }
}

// ================================================================ launcher
extern "C" void kernel_launch(void* const* d_in, const int* in_sizes, int n_in,
                              void* d_out, int out_size, void* d_ws, size_t ws_size,
                              hipStream_t stream) {
  const float* single = (const float*)d_in[0];
  const float* pair   = (const float*)d_in[1];
  const float* rot    = (const float*)d_in[2];
  const float* trans  = (const float*)d_in[3];
  const float* mask   = (const float*)d_in[4];
  const float* ln_w   = (const float*)d_in[5];
  const float* ln_b   = (const float*)d_in[6];
  const float* Wq     = (const float*)d_in[7];
  const float* bq     = (const float*)d_in[8];
  const float* Wk     = (const float*)d_in[9];
  const float* bk     = (const float*)d_in[10];
  const float* Wv     = (const float*)d_in[11];
  const float* bv     = (const float*)d_in[12];
  const float* Wqp    = (const float*)d_in[13];
  const float* bqp    = (const float*)d_in[14];
  const float* Wkp    = (const float*)d_in[15];
  const float* bkp    = (const float*)d_in[16];
  const float* Wvp    = (const float*)d_in[17];
  const float* bvp    = (const float*)d_in[18];
  const float* Wpb    = (const float*)d_in[19];
  const float* bpb    = (const float*)d_in[20];
  const float* Wo     = (const float*)d_in[21];
  const float* bo     = (const float*)d_in[22];
  const float* w_c    = (const float*)d_in[23];
  const float* w_l    = (const float*)d_in[24];
  const float* gamma  = (const float*)d_in[25];
  float* out = (float*)d_out;

  float* p = (float*)d_ws;
  auto alloc = [&](size_t n) { float* r = p; p += n; return r; };
  float* Wcat    = alloc((size_t)DS*NPP);
  float* bcat    = alloc(NPP);
  float* WpbT    = alloc((size_t)NH*DPAIR);
  float* sn      = alloc((size_t)LQ*DS);
  float* C1      = alloc((size_t)LQ*NPP);
  float* vgb     = alloc((size_t)LQ*NH*24);
  float* Af      = alloc((size_t)NH*LQ*FE);
  float* Bf      = alloc((size_t)NH*LQ*FE);
  float* S       = alloc((size_t)NH*LQ*LQ);
  float* pairpart= alloc((size_t)LQ*NC*NH*DPAIR);
  float* msum    = alloc((size_t)LQ*NC*NH*2);
  float* scs_g   = alloc((size_t)LQ*NH*NC);
  float* comb    = alloc((size_t)LQ*2304);
  float* scratch = alloc((size_t)2*LQ*NPP);  // proj partials (2*512*1792) >= psum (4*512*768) >= out partials (8*512*384)

  k_concat_w<<<dim3((DS*NPP + NPP + DPAIR*NH + 255)/256), 256, 0, stream>>>(
      Wq, Wk, Wv, Wqp, Wkp, Wvp, bq, bk, bv, bqp, bkp, bvp, Wpb, Wcat, bcat, WpbT);
  k_layernorm<<<dim3(LQ), 128, 0, stream>>>(single, ln_w, ln_b, sn);
  k_gemm_nn<<<dim3(NPP/64, LQ/64, 2), 256, 0, stream>>>(sn, Wcat, nullptr, nullptr, scratch, LQ, NPP, DS);
  k_reduce_bias<<<dim3((LQ*NPP + 255)/256), 256, 0, stream>>>(scratch, bcat, C1, LQ*NPP, NPP, 2);
  k_rotfeat<<<dim3((LQ*NH + 255)/256), 256, 0, stream>>>(C1, rot, trans, gamma, w_c, w_l, Af, Bf, vgb);
  k_logits_nt<<<dim3(LQ/64, LQ/64, NH), 256, 0, stream>>>(Af, Bf, S);
  k_pair_chunk<<<dim3(LQ, NC), 256, 0, stream>>>(pair, WpbT, bpb, mask, S, pairpart, msum);
  k_scs_pairout<<<dim3(LQ), 384, 0, stream>>>(msum, pairpart, scs_g, comb);
  k_attn_v<<<dim3(LQ/64, NH, 4), 256, 0, stream>>>(S, C1, vgb, scs_g, scratch);
  k_avpts<<<dim3((LQ*NH*40 + 255)/256), 256, 0, stream>>>(scratch, rot, trans, comb);
  k_gemm_nn<<<dim3(DS/64, LQ/64, 8), 256, 0, stream>>>(comb, Wo, nullptr, nullptr, scratch, LQ, DS, 2304);
  k_reduce_bias<<<dim3((LQ*DS + 255)/256), 256, 0, stream>>>(scratch, bo, out, LQ*DS, DS, 8);
}